// Round 5
// baseline (239.521 us; speedup 1.0000x reference)
//
#include <hip/hip_runtime.h>
#include <stdint.h>

// ---------------- problem constants ----------------
#define BB 2
#define SS 2048
#define EE 1024
#define HH 16
#define DHD 64
#define MM (BB*SS)          // 4096 tokens
// scale * log2(e): fold log2e into Q so softmax uses exp2 (v_exp_f32) directly
#define QSCALE (0.125f * 1.4426950408889634f)

typedef __bf16 bf16;
typedef __bf16 bf16x8 __attribute__((ext_vector_type(8)));
typedef __bf16 bf16x4 __attribute__((ext_vector_type(4)));
typedef float  f32x4  __attribute__((ext_vector_type(4)));
typedef unsigned short ushort8 __attribute__((ext_vector_type(8)));

#define MFMA16(a,b,c) __builtin_amdgcn_mfma_f32_16x16x32_bf16(a,b,c,0,0,0)

__device__ __forceinline__ void gload_lds16(const void* g, void* l) {
  __builtin_amdgcn_global_load_lds(
      (const __attribute__((address_space(1))) unsigned int*)g,
      (__attribute__((address_space(3))) unsigned int*)l, 16, 0, 0);
}

__device__ __forceinline__ unsigned short f2bf(float f) {
  union { float f; unsigned u; } v; v.f = f;
  return (unsigned short)((v.u + 0x7FFFu + ((v.u >> 16) & 1u)) >> 16);
}

// ---------------- kernel 0: fp32 -> bf16 conversion ----------------
__global__ void convert_kernel(const float* __restrict__ x,
                               const float* __restrict__ wq, const float* __restrict__ wk,
                               const float* __restrict__ wv, const float* __restrict__ wo,
                               unsigned short* __restrict__ xbf,
                               unsigned short* __restrict__ wqb, unsigned short* __restrict__ wkb,
                               unsigned short* __restrict__ wvb, unsigned short* __restrict__ wob) {
  long t = (long)blockIdx.x * blockDim.x + threadIdx.x;  // 1M threads
  long base = t * 8;
  const float* src; unsigned short* dst; long off;
  if (base < 4194304L) { src = x; dst = xbf; off = base; }
  else {
    long r = base - 4194304L; int j = (int)(r >> 20); off = r & 1048575L;
    src = (j==0)?wq:(j==1)?wk:(j==2)?wv:wo;
    dst = (j==0)?wqb:(j==1)?wkb:(j==2)?wvb:wob;
  }
  const float4* s4 = (const float4*)(src + off);
  float4 a = s4[0], b = s4[1];
  ushort8 o;
  o[0]=f2bf(a.x); o[1]=f2bf(a.y); o[2]=f2bf(a.z); o[3]=f2bf(a.w);
  o[4]=f2bf(b.x); o[5]=f2bf(b.y); o[6]=f2bf(b.z); o[7]=f2bf(b.w);
  *(ushort8*)(dst + off) = o;
}

// ---- shared GEMM K-loop staging (dbuf, counted vmcnt, raw barriers) ----
#define G_STAGE(kbuf, kt) { \
    const size_t kb_ = (size_t)(kt) * 64; \
    char* d_ = lds + (kbuf) * 16384 + tid * 16; \
    gload_lds16(a0 + kb_, d_); \
    gload_lds16(a1 + kb_, d_ + 4096); \
    gload_lds16(b0 + kb_, d_ + 8192); \
    gload_lds16(b1 + kb_, d_ + 12288); \
  }

// ---------------- kernel 1: fused QKV projection GEMM (dbuf pipeline) ----------------
// C[m, n'] = x[m,:] . W[n,:] (+bias); proj = n'>>10 -> (Wq,Q)/(Wk,K)/(Wv,V^T)
__global__ __launch_bounds__(256) void qkv_gemm(
    const bf16* __restrict__ xbf,
    const bf16* __restrict__ wqb, const bf16* __restrict__ wkb, const bf16* __restrict__ wvb,
    const float* __restrict__ bq, const float* __restrict__ bk, const float* __restrict__ bv,
    bf16* __restrict__ Q, bf16* __restrict__ K, bf16* __restrict__ VT) {
  __shared__ char lds[32768] __attribute__((aligned(16)));
  const int tid = threadIdx.x;
  const int bm = blockIdx.y * 128;
  const int bnG = blockIdx.x * 128;
  const int proj = bnG >> 10;
  const int bn = bnG & 1023;
  const bf16* wsel = (proj==0)?wqb:(proj==1)?wkb:wvb;
  const float* bias = (proj==0)?bq:(proj==1)?bk:bv;

  const int lane = tid & 63, w = tid >> 6;
  const int wm = (w>>1)*64, wn = (w&1)*64;
  const int c = lane & 15, g = lane >> 4;

  const int sr = tid >> 2;
  const int scb = ((tid & 3) * 16) ^ ((sr & 3) << 4);
  const char* a0 = (const char*)xbf  + ((size_t)(bm + sr     ) * 1024) * 2 + scb;
  const char* a1 = (const char*)xbf  + ((size_t)(bm + 64 + sr) * 1024) * 2 + scb;
  const char* b0 = (const char*)wsel + ((size_t)(bn + sr     ) * 1024) * 2 + scb;
  const char* b1 = (const char*)wsel + ((size_t)(bn + 64 + sr) * 1024) * 2 + scb;

  int aoff[4], boff[4];
#pragma unroll
  for (int mt=0; mt<4; ++mt) { int rr = wm + mt*16 + c; aoff[mt] = rr*64 + ((g*16) ^ ((rr&3)<<4)); }
#pragma unroll
  for (int nt=0; nt<4; ++nt) { int rr = wn + nt*16 + c; boff[nt] = 8192 + rr*64 + ((g*16) ^ ((rr&3)<<4)); }

  f32x4 acc[4][4];
#pragma unroll
  for (int mt=0; mt<4; ++mt)
#pragma unroll
    for (int nt=0; nt<4; ++nt) acc[mt][nt] = (f32x4){0.f,0.f,0.f,0.f};

  G_STAGE(0, 0);
  for (int kt = 0; kt < 32; ++kt) {
    const int cur = kt & 1;
    if (kt < 31) {
      G_STAGE(cur ^ 1, kt + 1);
      asm volatile("s_waitcnt vmcnt(4)" ::: "memory");   // current tile's 4 loads done
    } else {
      asm volatile("s_waitcnt vmcnt(0)" ::: "memory");
    }
    __builtin_amdgcn_s_barrier();
    const char* Ts = lds + cur * 16384;
    bf16x8 af[4], bfv[4];
#pragma unroll
    for (int mt=0; mt<4; ++mt) af[mt] = *(const bf16x8*)(Ts + aoff[mt]);
#pragma unroll
    for (int nt=0; nt<4; ++nt) bfv[nt] = *(const bf16x8*)(Ts + boff[nt]);
#pragma unroll
    for (int mt=0; mt<4; ++mt)
#pragma unroll
      for (int nt=0; nt<4; ++nt)
        acc[mt][nt] = MFMA16(af[mt], bfv[nt], acc[mt][nt]);
    asm volatile("s_waitcnt lgkmcnt(0)" ::: "memory");   // my LDS reads retired
    __builtin_amdgcn_s_barrier();                        // safe to overwrite cur
  }

  const int bidx = bm >> 11;
  const int srow = bm & 2047;
#pragma unroll
  for (int nt=0; nt<4; ++nt) {
    const int n = bn + wn + nt*16 + c;
    const float bv_ = bias[n];
    const int h = n >> 6, d = n & 63;
#pragma unroll
    for (int mt=0; mt<4; ++mt) {
      f32x4 a = acc[mt][nt];
      const int m0 = wm + mt*16 + g*4;
      if (proj == 0) {
#pragma unroll
        for (int r=0;r<4;++r) {
          int s = srow + m0 + r;
          Q[(((size_t)(bidx*16 + h))*2048 + s)*64 + d] = (bf16)((a[r] + bv_) * QSCALE);
        }
      } else if (proj == 1) {
#pragma unroll
        for (int r=0;r<4;++r) {
          int s = srow + m0 + r;
          K[(((size_t)(bidx*16 + h))*2048 + s)*64 + d] = (bf16)(a[r] + bv_);
        }
      } else {
        bf16x4 pk;
#pragma unroll
        for (int r=0;r<4;++r) pk[r] = (bf16)(a[r] + bv_);
        *(bf16x4*)(VT + (((size_t)(bidx*16 + h))*64 + d)*2048 + (srow + m0)) = pk;
      }
    }
  }
}

// ---------------- kernel 2: flash attention v3 (defer-max, max3, setprio) ----------------
__global__ __launch_bounds__(256) void attn_kernel(
    const bf16* __restrict__ Q, const bf16* __restrict__ K,
    const bf16* __restrict__ VT, bf16* __restrict__ attn_out) {
  __shared__ char alds[32768] __attribute__((aligned(16)));
  const int tid = threadIdx.x;
  const int lane = tid & 63, w = tid >> 6;
  const int c = lane & 15, g = lane >> 4;
  const int x7 = c & 7;
  const int bh = blockIdx.y;                      // b*16 + h
  const int qb = blockIdx.x * 64 + w * 16;        // wave's q base
  const bf16* Qh = Q + (size_t)bh * 2048 * 64;
  const char* Khb = (const char*)(K  + (size_t)bh * 2048 * 64);
  const char* Vhb = (const char*)(VT + (size_t)bh * 64 * 2048);

  // staging: LDS(row, chunk) <- global(row, chunk ^ (row&7)); row=tid>>3, chunk=tid&7
  const int srow = tid >> 3, schunk = tid & 7;
  const int ssw = ((schunk ^ (srow & 7)) << 4);
  const char* srcK = Khb + (size_t)srow * 128  + ssw;
  const char* srcV = Vhb + (size_t)srow * 4096 + ssw;

#define ATT_STAGE(buf, kv) { \
    const char* sk_ = srcK + (size_t)(kv) * 128; \
    const char* sv_ = srcV + (size_t)(kv) * 2; \
    char* d_ = alds + (buf) * 16384 + tid * 16; \
    gload_lds16(sk_,            d_); \
    gload_lds16(sk_ + 32*128,   d_ + 4096); \
    gload_lds16(sv_,            d_ + 8192); \
    gload_lds16(sv_ + 32*4096,  d_ + 12288); \
  }

  // Q fragments (B-operand): lane holds q = qb+c, d = kk*32 + g*8 + j
  bf16x8 qf0 = *(const bf16x8*)(Qh + (size_t)(qb + c)*64 + g*8);
  bf16x8 qf1 = *(const bf16x8*)(Qh + (size_t)(qb + c)*64 + 32 + g*8);

  f32x4 o[4];
#pragma unroll
  for (int dt=0; dt<4; ++dt) o[dt] = (f32x4){0.f,0.f,0.f,0.f};
  float m = -1e30f, l = 0.f;

  ATT_STAGE(0, 0);
  for (int t = 0; t < 32; ++t) {
    const int cur = t & 1;
    if (t < 31) {
      ATT_STAGE(cur ^ 1, (t + 1) * 64);
      asm volatile("s_waitcnt vmcnt(4)" ::: "memory");
    } else {
      asm volatile("s_waitcnt vmcnt(0)" ::: "memory");
    }
    __builtin_amdgcn_s_barrier();

    const char* Kl = alds + cur * 16384;
    const char* Vl = Kl + 8192;

    // QK^T (swapped): st[ks] = scores for keys ks*16 + 4g + r, q = qb+c
    f32x4 st[4];
    __builtin_amdgcn_s_setprio(1);
#pragma unroll
    for (int ks = 0; ks < 4; ++ks) {
      const char* kr = Kl + (ks*16 + c) * 128;
      bf16x8 k0 = *(const bf16x8*)(kr + (((g    ) ^ x7) << 4));
      bf16x8 k1 = *(const bf16x8*)(kr + (((g + 4) ^ x7) << 4));
      f32x4 z = (f32x4){0.f,0.f,0.f,0.f};
      z = MFMA16(k0, qf0, z);
      z = MFMA16(k1, qf1, z);
      st[ks] = z;
    }
    __builtin_amdgcn_s_setprio(0);

    // tile max via max3-friendly triples (8 ops instead of 15)
    float m0_ = fmaxf(fmaxf(st[0][0], st[0][1]), st[0][2]);
    float m1_ = fmaxf(fmaxf(st[0][3], st[1][0]), st[1][1]);
    float m2_ = fmaxf(fmaxf(st[1][2], st[1][3]), st[2][0]);
    float m3_ = fmaxf(fmaxf(st[2][1], st[2][2]), st[2][3]);
    float m4_ = fmaxf(fmaxf(st[3][0], st[3][1]), st[3][2]);
    float tmax = fmaxf(fmaxf(fmaxf(m0_, m1_), m2_), fmaxf(fmaxf(m3_, m4_), st[3][3]));
    tmax = fmaxf(tmax, __shfl_xor(tmax, 16, 64));
    tmax = fmaxf(tmax, __shfl_xor(tmax, 32, 64));

    float p[4][4]; float ps = 0.f;
    if (__all(tmax <= m + 8.f)) {
      // defer-max: keep old m, P bounded by 2^8 (bf16-safe), no o-rescale
#pragma unroll
      for (int ks = 0; ks < 4; ++ks)
#pragma unroll
        for (int r = 0; r < 4; ++r) { p[ks][r] = __builtin_exp2f(st[ks][r] - m); ps += p[ks][r]; }
      ps += __shfl_xor(ps, 16, 64);
      ps += __shfl_xor(ps, 32, 64);
      l += ps;
    } else {
      const float mnew = fmaxf(m, tmax);
      const float corr = __builtin_exp2f(m - mnew);
#pragma unroll
      for (int ks = 0; ks < 4; ++ks)
#pragma unroll
        for (int r = 0; r < 4; ++r) { p[ks][r] = __builtin_exp2f(st[ks][r] - mnew); ps += p[ks][r]; }
      ps += __shfl_xor(ps, 16, 64);
      ps += __shfl_xor(ps, 32, 64);
      l = l * corr + ps;
      m = mnew;
#pragma unroll
      for (int dt=0; dt<4; ++dt) o[dt] *= corr;
    }

    // P fragments, permuted-k (lane-local): slot (g,j<4) = key 4g+j (+16 for j>=4)
    bf16x8 pfA, pfB;
#pragma unroll
    for (int r = 0; r < 4; ++r) {
      pfA[r] = (bf16)p[0][r]; pfA[4+r] = (bf16)p[1][r];
      pfB[r] = (bf16)p[2][r]; pfB[4+r] = (bf16)p[3][r];
    }

    // PV: O^T[d][q] += V^T[d][key]*P^T[key][q]; V read with same key permutation
    const int i8 = (g & 1) * 8, gh = g >> 1;
    __builtin_amdgcn_s_setprio(1);
#pragma unroll
    for (int dt = 0; dt < 4; ++dt) {
      const char* vr = Vl + (dt*16 + c) * 128;
      bf16x4 va0 = *(const bf16x4*)(vr + (((gh    ) ^ x7) << 4) + i8);   // keys  4g..
      bf16x4 va1 = *(const bf16x4*)(vr + (((gh + 2) ^ x7) << 4) + i8);   // keys 16+4g..
      bf16x4 vb0 = *(const bf16x4*)(vr + (((gh + 4) ^ x7) << 4) + i8);   // keys 32+4g..
      bf16x4 vb1 = *(const bf16x4*)(vr + (((gh + 6) ^ x7) << 4) + i8);   // keys 48+4g..
      bf16x8 vfA = __builtin_shufflevector(va0, va1, 0,1,2,3,4,5,6,7);
      bf16x8 vfB = __builtin_shufflevector(vb0, vb1, 0,1,2,3,4,5,6,7);
      o[dt] = MFMA16(vfA, pfA, o[dt]);
      o[dt] = MFMA16(vfB, pfB, o[dt]);
    }
    __builtin_amdgcn_s_setprio(0);

    asm volatile("s_waitcnt lgkmcnt(0)" ::: "memory");
    __builtin_amdgcn_s_barrier();
  }
#undef ATT_STAGE

  const float inv = 1.0f / l;
  const int srow_q = qb + c;
  const int b = bh >> 4, h = bh & 15;
  bf16* outrow = attn_out + ((size_t)(b*2048 + srow_q))*1024 + h*64;
#pragma unroll
  for (int dt=0; dt<4; ++dt) {
    bf16x4 ov;
#pragma unroll
    for (int r=0;r<4;++r) ov[r] = (bf16)(o[dt][r] * inv);
    *(bf16x4*)(outrow + dt*16 + g*4) = ov;
  }
}

// ---------------- kernel 3: output projection GEMM (dbuf pipeline) ----------------
__global__ __launch_bounds__(256) void out_gemm(
    const bf16* __restrict__ A, const bf16* __restrict__ W,
    const float* __restrict__ bias, float* __restrict__ out) {
  __shared__ char lds[32768] __attribute__((aligned(16)));
  const int tid = threadIdx.x;
  const int bm = blockIdx.y * 128, bn = blockIdx.x * 128;
  const int lane = tid & 63, w = tid >> 6;
  const int wm = (w>>1)*64, wn = (w&1)*64;
  const int c = lane & 15, g = lane >> 4;

  const int sr = tid >> 2;
  const int scb = ((tid & 3) * 16) ^ ((sr & 3) << 4);
  const char* a0 = (const char*)A + ((size_t)(bm + sr     ) * 1024) * 2 + scb;
  const char* a1 = (const char*)A + ((size_t)(bm + 64 + sr) * 1024) * 2 + scb;
  const char* b0 = (const char*)W + ((size_t)(bn + sr     ) * 1024) * 2 + scb;
  const char* b1 = (const char*)W + ((size_t)(bn + 64 + sr) * 1024) * 2 + scb;

  int aoff[4], boff[4];
#pragma unroll
  for (int mt=0; mt<4; ++mt) { int rr = wm + mt*16 + c; aoff[mt] = rr*64 + ((g*16) ^ ((rr&3)<<4)); }
#pragma unroll
  for (int nt=0; nt<4; ++nt) { int rr = wn + nt*16 + c; boff[nt] = 8192 + rr*64 + ((g*16) ^ ((rr&3)<<4)); }

  f32x4 acc[4][4];
#pragma unroll
  for (int mt=0; mt<4; ++mt)
#pragma unroll
    for (int nt=0; nt<4; ++nt) acc[mt][nt] = (f32x4){0.f,0.f,0.f,0.f};

  G_STAGE(0, 0);
  for (int kt = 0; kt < 32; ++kt) {
    const int cur = kt & 1;
    if (kt < 31) {
      G_STAGE(cur ^ 1, kt + 1);
      asm volatile("s_waitcnt vmcnt(4)" ::: "memory");
    } else {
      asm volatile("s_waitcnt vmcnt(0)" ::: "memory");
    }
    __builtin_amdgcn_s_barrier();
    const char* Ts = lds + cur * 16384;
    bf16x8 af[4], bfv[4];
#pragma unroll
    for (int mt=0; mt<4; ++mt) af[mt] = *(const bf16x8*)(Ts + aoff[mt]);
#pragma unroll
    for (int nt=0; nt<4; ++nt) bfv[nt] = *(const bf16x8*)(Ts + boff[nt]);
#pragma unroll
    for (int mt=0; mt<4; ++mt)
#pragma unroll
      for (int nt=0; nt<4; ++nt)
        acc[mt][nt] = MFMA16(af[mt], bfv[nt], acc[mt][nt]);
    asm volatile("s_waitcnt lgkmcnt(0)" ::: "memory");
    __builtin_amdgcn_s_barrier();
  }

#pragma unroll
  for (int nt=0; nt<4; ++nt) {
    const int n = bn + wn + nt*16 + c;
    const float bv_ = bias[n];
#pragma unroll
    for (int mt=0; mt<4; ++mt) {
      const int m0 = bm + wm + mt*16 + g*4;
#pragma unroll
      for (int r=0;r<4;++r) out[(size_t)(m0 + r)*1024 + n] = acc[mt][nt][r] + bv_;
    }
  }
}

// ---------------- launch ----------------
extern "C" void kernel_launch(void* const* d_in, const int* in_sizes, int n_in,
                              void* d_out, int out_size, void* d_ws, size_t ws_size,
                              hipStream_t stream) {
  const float* x  = (const float*)d_in[0];
  const float* Wq = (const float*)d_in[1];
  const float* bq = (const float*)d_in[2];
  const float* Wk = (const float*)d_in[3];
  const float* bk = (const float*)d_in[4];
  const float* Wv = (const float*)d_in[5];
  const float* bv = (const float*)d_in[6];
  const float* Wo = (const float*)d_in[7];
  const float* bo = (const float*)d_in[8];

  char* ws = (char*)d_ws;
  const size_t MiB = 1u << 20;
  unsigned short* xbf = (unsigned short*)(ws);              // 8 MiB
  unsigned short* wqb = (unsigned short*)(ws +  8*MiB);     // 2 MiB
  unsigned short* wkb = (unsigned short*)(ws + 10*MiB);
  unsigned short* wvb = (unsigned short*)(ws + 12*MiB);
  unsigned short* wob = (unsigned short*)(ws + 14*MiB);
  bf16* Qb    = (bf16*)(ws + 16*MiB);                       // 8 MiB [B,H,S,DH]
  bf16* Kb    = (bf16*)(ws + 24*MiB);                       // 8 MiB [B,H,S,DH]
  bf16* VTb   = (bf16*)(ws + 32*MiB);                       // 8 MiB [B,H,DH,S]
  bf16* attnb = (bf16*)(ws + 40*MiB);                       // 8 MiB [M,E]

  convert_kernel<<<4096, 256, 0, stream>>>(x, Wq, Wk, Wv, Wo, xbf, wqb, wkb, wvb, wob);
  qkv_gemm<<<dim3(24, 32), 256, 0, stream>>>(
      (const bf16*)xbf, (const bf16*)wqb, (const bf16*)wkb, (const bf16*)wvb,
      bq, bk, bv, Qb, Kb, VTb);
  attn_kernel<<<dim3(32, 32), 256, 0, stream>>>(Qb, Kb, VTb, attnb);
  out_gemm<<<dim3(8, 32), 256, 0, stream>>>(attnb, (const bf16*)wob, bo, (float*)d_out);
}

// Round 7
// 232.975 us; speedup vs baseline: 1.0281x; 1.0281x over previous
//
#include <hip/hip_runtime.h>
#include <stdint.h>

// ---------------- problem constants ----------------
#define BB 2
#define SS 2048
#define EE 1024
#define HH 16
#define DHD 64
#define MM (BB*SS)          // 4096 tokens
// scale * log2(e): fold log2e into Q so softmax uses exp2 (v_exp_f32) directly
#define QSCALE (0.125f * 1.4426950408889634f)

typedef __bf16 bf16;
typedef __bf16 bf16x8 __attribute__((ext_vector_type(8)));
typedef __bf16 bf16x4 __attribute__((ext_vector_type(4)));
typedef float  f32x4  __attribute__((ext_vector_type(4)));
typedef unsigned short ushort8 __attribute__((ext_vector_type(8)));

#define MFMA16(a,b,c) __builtin_amdgcn_mfma_f32_16x16x32_bf16(a,b,c,0,0,0)

__device__ __forceinline__ void gload_lds16(const void* g, void* l) {
  __builtin_amdgcn_global_load_lds(
      (const __attribute__((address_space(1))) unsigned int*)g,
      (__attribute__((address_space(3))) unsigned int*)l, 16, 0, 0);
}

__device__ __forceinline__ unsigned short f2bf(float f) {
  union { float f; unsigned u; } v; v.f = f;
  return (unsigned short)((v.u + 0x7FFFu + ((v.u >> 16) & 1u)) >> 16);
}

// ---------------- kernel 0: fp32 -> bf16 conversion ----------------
__global__ void convert_kernel(const float* __restrict__ x,
                               const float* __restrict__ wq, const float* __restrict__ wk,
                               const float* __restrict__ wv, const float* __restrict__ wo,
                               unsigned short* __restrict__ xbf,
                               unsigned short* __restrict__ wqb, unsigned short* __restrict__ wkb,
                               unsigned short* __restrict__ wvb, unsigned short* __restrict__ wob) {
  long t = (long)blockIdx.x * blockDim.x + threadIdx.x;  // 1M threads
  long base = t * 8;
  const float* src; unsigned short* dst; long off;
  if (base < 4194304L) { src = x; dst = xbf; off = base; }
  else {
    long r = base - 4194304L; int j = (int)(r >> 20); off = r & 1048575L;
    src = (j==0)?wq:(j==1)?wk:(j==2)?wv:wo;
    dst = (j==0)?wqb:(j==1)?wkb:(j==2)?wvb:wob;
  }
  const float4* s4 = (const float4*)(src + off);
  float4 a = s4[0], b = s4[1];
  ushort8 o;
  o[0]=f2bf(a.x); o[1]=f2bf(a.y); o[2]=f2bf(a.z); o[3]=f2bf(a.w);
  o[4]=f2bf(b.x); o[5]=f2bf(b.y); o[6]=f2bf(b.z); o[7]=f2bf(b.w);
  *(ushort8*)(dst + off) = o;
}

// ---- shared GEMM K-loop (dbuf, counted vmcnt, raw barriers) ----
// SWAP=false: acc = A-tile x B-tile   -> lane(c,g) reg r = C[m=g*4+r][n=c]
// SWAP=true : acc = B-tile x A-tile   -> lane(c,g) reg r = C[m=c][n=g*4+r]
//             (4 consecutive n per lane -> wide C-stores along n)
#define GS_STAGE(kbuf, kt) { \
    const size_t kb_ = (size_t)(kt) * 64; \
    char* d_ = lds + (kbuf) * 16384 + tid * 16; \
    gload_lds16(a0 + kb_, d_); \
    gload_lds16(a1 + kb_, d_ + 4096); \
    gload_lds16(b0 + kb_, d_ + 8192); \
    gload_lds16(b1 + kb_, d_ + 12288); \
  }

template<bool SWAP>
__device__ __forceinline__ void gemm_kloop(
    const char* a0, const char* a1, const char* b0, const char* b1,
    char* lds, const int tid, const int (&aoff)[4], const int (&boff)[4],
    f32x4 (&acc)[4][4]) {
  GS_STAGE(0, 0);
  for (int kt = 0; kt < 32; ++kt) {
    const int cur = kt & 1;
    if (kt < 31) {
      GS_STAGE(cur ^ 1, kt + 1);
      asm volatile("s_waitcnt vmcnt(4)" ::: "memory");   // current tile's 4 loads done
    } else {
      asm volatile("s_waitcnt vmcnt(0)" ::: "memory");
    }
    __builtin_amdgcn_s_barrier();
    const char* Ts = lds + cur * 16384;
    bf16x8 af[4], bfv[4];
#pragma unroll
    for (int mt=0; mt<4; ++mt) af[mt] = *(const bf16x8*)(Ts + aoff[mt]);
#pragma unroll
    for (int nt=0; nt<4; ++nt) bfv[nt] = *(const bf16x8*)(Ts + boff[nt]);
#pragma unroll
    for (int mt=0; mt<4; ++mt)
#pragma unroll
      for (int nt=0; nt<4; ++nt)
        acc[mt][nt] = SWAP ? MFMA16(bfv[nt], af[mt], acc[mt][nt])
                           : MFMA16(af[mt], bfv[nt], acc[mt][nt]);
    asm volatile("s_waitcnt lgkmcnt(0)" ::: "memory");   // my LDS reads retired
    __builtin_amdgcn_s_barrier();                        // safe to overwrite cur
  }
}

// ---------------- kernel 1: fused QKV projection GEMM ----------------
// C[m, n'] = x[m,:] . W[n,:] (+bias); proj = n'>>10 -> (Wq,Q)/(Wk,K)/(Wv,V^T)
// proj 0/1 use SWAP=true (wide d-contiguous stores); proj 2 keeps SWAP=false
// (bf16x4 along s for the V^T layout).
__global__ __launch_bounds__(256) void qkv_gemm(
    const bf16* __restrict__ xbf,
    const bf16* __restrict__ wqb, const bf16* __restrict__ wkb, const bf16* __restrict__ wvb,
    const float* __restrict__ bq, const float* __restrict__ bk, const float* __restrict__ bv,
    bf16* __restrict__ Q, bf16* __restrict__ K, bf16* __restrict__ VT) {
  __shared__ char lds[32768] __attribute__((aligned(16)));
  const int tid = threadIdx.x;
  const int bm = blockIdx.y * 128;
  const int bnG = blockIdx.x * 128;
  const int proj = bnG >> 10;
  const int bn = bnG & 1023;
  const bf16* wsel = (proj==0)?wqb:(proj==1)?wkb:wvb;
  const float* bias = (proj==0)?bq:(proj==1)?bk:bv;

  const int lane = tid & 63, w = tid >> 6;
  const int wm = (w>>1)*64, wn = (w&1)*64;
  const int c = lane & 15, g = lane >> 4;

  const int sr = tid >> 2;
  const int scb = ((tid & 3) * 16) ^ ((sr & 3) << 4);
  const char* a0 = (const char*)xbf  + ((size_t)(bm + sr     ) * 1024) * 2 + scb;
  const char* a1 = (const char*)xbf  + ((size_t)(bm + 64 + sr) * 1024) * 2 + scb;
  const char* b0 = (const char*)wsel + ((size_t)(bn + sr     ) * 1024) * 2 + scb;
  const char* b1 = (const char*)wsel + ((size_t)(bn + 64 + sr) * 1024) * 2 + scb;

  int aoff[4], boff[4];
#pragma unroll
  for (int mt=0; mt<4; ++mt) { int rr = wm + mt*16 + c; aoff[mt] = rr*64 + ((g*16) ^ ((rr&3)<<4)); }
#pragma unroll
  for (int nt=0; nt<4; ++nt) { int rr = wn + nt*16 + c; boff[nt] = 8192 + rr*64 + ((g*16) ^ ((rr&3)<<4)); }

  f32x4 acc[4][4];
#pragma unroll
  for (int mt=0; mt<4; ++mt)
#pragma unroll
    for (int nt=0; nt<4; ++nt) acc[mt][nt] = (f32x4){0.f,0.f,0.f,0.f};

  const int bidx = bm >> 11;
  const int srow = bm & 2047;

  if (proj != 2) {
    gemm_kloop<true>(a0, a1, b0, b1, lds, tid, aoff, boff, acc);
    // lane(c,g) reg r = C[m = wm+mt*16+c][n = wn+nt*16+g*4+r]
    bf16* dst = (proj == 0) ? Q : K;
    const float qs = (proj == 0) ? QSCALE : 1.0f;
#pragma unroll
    for (int nt=0; nt<4; ++nt) {
      const int n0 = bn + wn + nt*16 + g*4;          // 4-aligned, within one head
      const float4 b4 = *(const float4*)(bias + n0);
      const int h = n0 >> 6, d0 = n0 & 63;
#pragma unroll
      for (int mt=0; mt<4; ++mt) {
        const int s = srow + wm + mt*16 + c;
        bf16x4 pk;
        pk[0] = (bf16)((acc[mt][nt][0] + b4.x) * qs);
        pk[1] = (bf16)((acc[mt][nt][1] + b4.y) * qs);
        pk[2] = (bf16)((acc[mt][nt][2] + b4.z) * qs);
        pk[3] = (bf16)((acc[mt][nt][3] + b4.w) * qs);
        *(bf16x4*)(dst + (((size_t)(bidx*16 + h))*2048 + s)*64 + d0) = pk;
      }
    }
  } else {
    gemm_kloop<false>(a0, a1, b0, b1, lds, tid, aoff, boff, acc);
    // lane(c,g) reg r = C[m = wm+mt*16+g*4+r][n = wn+nt*16+c]
#pragma unroll
    for (int nt=0; nt<4; ++nt) {
      const int n = bn + wn + nt*16 + c;
      const float bv_ = bias[n];
      const int h = n >> 6, d = n & 63;
#pragma unroll
      for (int mt=0; mt<4; ++mt) {
        const int m0 = wm + mt*16 + g*4;
        bf16x4 pk;
#pragma unroll
        for (int r=0;r<4;++r) pk[r] = (bf16)(acc[mt][nt][r] + bv_);
        *(bf16x4*)(VT + (((size_t)(bidx*16 + h))*64 + d)*2048 + (srow + m0)) = pk;
      }
    }
  }
}

// ---------------- kernel 2: flash attention (R4 version) ----------------
// grid = (S/64, B*H), 4 waves/block, wave owns 16 q-rows. KVBLK=64.
// K tile [64 keys][64 d] and V tile [64 d][64 keys] staged to LDS via
// global_load_lds (shared across the 4 waves), double-buffered with counted
// vmcnt(4) + raw s_barrier. 16B-chunk XOR swizzle both sides.
__global__ __launch_bounds__(256) void attn_kernel(
    const bf16* __restrict__ Q, const bf16* __restrict__ K,
    const bf16* __restrict__ VT, bf16* __restrict__ attn_out) {
  __shared__ char alds[32768] __attribute__((aligned(16)));
  const int tid = threadIdx.x;
  const int lane = tid & 63, w = tid >> 6;
  const int c = lane & 15, g = lane >> 4;
  const int x7 = c & 7;
  const int bh = blockIdx.y;                      // b*16 + h
  const int qb = blockIdx.x * 64 + w * 16;        // wave's q base
  const bf16* Qh = Q + (size_t)bh * 2048 * 64;
  const char* Khb = (const char*)(K  + (size_t)bh * 2048 * 64);
  const char* Vhb = (const char*)(VT + (size_t)bh * 64 * 2048);

  // staging: LDS(row, chunk) <- global(row, chunk ^ (row&7)); row=tid>>3, chunk=tid&7
  const int srow = tid >> 3, schunk = tid & 7;
  const int ssw = ((schunk ^ (srow & 7)) << 4);
  const char* srcK = Khb + (size_t)srow * 128  + ssw;
  const char* srcV = Vhb + (size_t)srow * 4096 + ssw;

#define ATT_STAGE(buf, kv) { \
    const char* sk_ = srcK + (size_t)(kv) * 128; \
    const char* sv_ = srcV + (size_t)(kv) * 2; \
    char* d_ = alds + (buf) * 16384 + tid * 16; \
    gload_lds16(sk_,            d_); \
    gload_lds16(sk_ + 32*128,   d_ + 4096); \
    gload_lds16(sv_,            d_ + 8192); \
    gload_lds16(sv_ + 32*4096,  d_ + 12288); \
  }

  // Q fragments (B-operand): lane holds q = qb+c, d = kk*32 + g*8 + j
  bf16x8 qf0 = *(const bf16x8*)(Qh + (size_t)(qb + c)*64 + g*8);
  bf16x8 qf1 = *(const bf16x8*)(Qh + (size_t)(qb + c)*64 + 32 + g*8);

  f32x4 o[4];
#pragma unroll
  for (int dt=0; dt<4; ++dt) o[dt] = (f32x4){0.f,0.f,0.f,0.f};
  float m = -1e30f, l = 0.f;

  ATT_STAGE(0, 0);
  for (int t = 0; t < 32; ++t) {
    const int cur = t & 1;
    if (t < 31) {
      ATT_STAGE(cur ^ 1, (t + 1) * 64);
      asm volatile("s_waitcnt vmcnt(4)" ::: "memory");
    } else {
      asm volatile("s_waitcnt vmcnt(0)" ::: "memory");
    }
    __builtin_amdgcn_s_barrier();

    const char* Kl = alds + cur * 16384;
    const char* Vl = Kl + 8192;

    // QK^T (swapped): st[ks] = scores for keys ks*16 + 4g + r, q = qb+c
    f32x4 st[4];
#pragma unroll
    for (int ks = 0; ks < 4; ++ks) {
      const char* kr = Kl + (ks*16 + c) * 128;
      bf16x8 k0 = *(const bf16x8*)(kr + (((g    ) ^ x7) << 4));
      bf16x8 k1 = *(const bf16x8*)(kr + (((g + 4) ^ x7) << 4));
      f32x4 z = (f32x4){0.f,0.f,0.f,0.f};
      z = MFMA16(k0, qf0, z);
      z = MFMA16(k1, qf1, z);
      st[ks] = z;
    }

    // online softmax over 64 keys (scores in log2 domain via QSCALE)
    float tmax = -1e30f;
#pragma unroll
    for (int ks = 0; ks < 4; ++ks)
      tmax = fmaxf(tmax, fmaxf(fmaxf(st[ks][0], st[ks][1]), fmaxf(st[ks][2], st[ks][3])));
    tmax = fmaxf(tmax, __shfl_xor(tmax, 16, 64));
    tmax = fmaxf(tmax, __shfl_xor(tmax, 32, 64));
    const float mnew = fmaxf(m, tmax);
    const float corr = __builtin_exp2f(m - mnew);
    float p[4][4]; float ps = 0.f;
#pragma unroll
    for (int ks = 0; ks < 4; ++ks)
#pragma unroll
      for (int r = 0; r < 4; ++r) { p[ks][r] = __builtin_exp2f(st[ks][r] - mnew); ps += p[ks][r]; }
    ps += __shfl_xor(ps, 16, 64);
    ps += __shfl_xor(ps, 32, 64);
    l = l * corr + ps;
    m = mnew;
#pragma unroll
    for (int dt=0; dt<4; ++dt) o[dt] *= corr;

    // P fragments, permuted-k (lane-local): slot (g,j<4) = key 4g+j (+16 for j>=4)
    bf16x8 pfA, pfB;
#pragma unroll
    for (int r = 0; r < 4; ++r) {
      pfA[r] = (bf16)p[0][r]; pfA[4+r] = (bf16)p[1][r];
      pfB[r] = (bf16)p[2][r]; pfB[4+r] = (bf16)p[3][r];
    }

    // PV: O^T[d][q] += V^T[d][key]*P^T[key][q]; V read with same key permutation
#pragma unroll
    for (int dt = 0; dt < 4; ++dt) {
      const char* vr = Vl + (dt*16 + c) * 128;
      const int i8 = (g & 1) * 8, gh = g >> 1;
      bf16x4 va0 = *(const bf16x4*)(vr + (((gh    ) ^ x7) << 4) + i8);   // keys  4g..
      bf16x4 va1 = *(const bf16x4*)(vr + (((gh + 2) ^ x7) << 4) + i8);   // keys 16+4g..
      bf16x4 vb0 = *(const bf16x4*)(vr + (((gh + 4) ^ x7) << 4) + i8);   // keys 32+4g..
      bf16x4 vb1 = *(const bf16x4*)(vr + (((gh + 6) ^ x7) << 4) + i8);   // keys 48+4g..
      bf16x8 vfA = __builtin_shufflevector(va0, va1, 0,1,2,3,4,5,6,7);
      bf16x8 vfB = __builtin_shufflevector(vb0, vb1, 0,1,2,3,4,5,6,7);
      o[dt] = MFMA16(vfA, pfA, o[dt]);
      o[dt] = MFMA16(vfB, pfB, o[dt]);
    }

    asm volatile("s_waitcnt lgkmcnt(0)" ::: "memory");
    __builtin_amdgcn_s_barrier();
  }
#undef ATT_STAGE

  const float inv = 1.0f / l;
  const int srow_q = qb + c;
  const int b = bh >> 4, h = bh & 15;
  bf16* outrow = attn_out + ((size_t)(b*2048 + srow_q))*1024 + h*64;
#pragma unroll
  for (int dt=0; dt<4; ++dt) {
    bf16x4 ov;
#pragma unroll
    for (int r=0;r<4;++r) ov[r] = (bf16)(o[dt][r] * inv);
    *(bf16x4*)(outrow + dt*16 + g*4) = ov;
  }
}

// ---------------- kernel 3: output projection GEMM (swapped, float4 stores) ----------------
__global__ __launch_bounds__(256) void out_gemm(
    const bf16* __restrict__ A, const bf16* __restrict__ W,
    const float* __restrict__ bias, float* __restrict__ out) {
  __shared__ char lds[32768] __attribute__((aligned(16)));
  const int tid = threadIdx.x;
  const int bm = blockIdx.y * 128, bn = blockIdx.x * 128;
  const int lane = tid & 63, w = tid >> 6;
  const int wm = (w>>1)*64, wn = (w&1)*64;
  const int c = lane & 15, g = lane >> 4;

  const int sr = tid >> 2;
  const int scb = ((tid & 3) * 16) ^ ((sr & 3) << 4);
  const char* a0 = (const char*)A + ((size_t)(bm + sr     ) * 1024) * 2 + scb;
  const char* a1 = (const char*)A + ((size_t)(bm + 64 + sr) * 1024) * 2 + scb;
  const char* b0 = (const char*)W + ((size_t)(bn + sr     ) * 1024) * 2 + scb;
  const char* b1 = (const char*)W + ((size_t)(bn + 64 + sr) * 1024) * 2 + scb;

  int aoff[4], boff[4];
#pragma unroll
  for (int mt=0; mt<4; ++mt) { int rr = wm + mt*16 + c; aoff[mt] = rr*64 + ((g*16) ^ ((rr&3)<<4)); }
#pragma unroll
  for (int nt=0; nt<4; ++nt) { int rr = wn + nt*16 + c; boff[nt] = 8192 + rr*64 + ((g*16) ^ ((rr&3)<<4)); }

  f32x4 acc[4][4];
#pragma unroll
  for (int mt=0; mt<4; ++mt)
#pragma unroll
    for (int nt=0; nt<4; ++nt) acc[mt][nt] = (f32x4){0.f,0.f,0.f,0.f};

  gemm_kloop<true>(a0, a1, b0, b1, lds, tid, aoff, boff, acc);

  // lane(c,g) reg r = C[m = bm+wm+mt*16+c][n = bn+wn+nt*16+g*4+r] -> float4 store
#pragma unroll
  for (int nt=0; nt<4; ++nt) {
    const int n0 = bn + wn + nt*16 + g*4;
    const float4 b4 = *(const float4*)(bias + n0);
#pragma unroll
    for (int mt=0; mt<4; ++mt) {
      const int m0 = bm + wm + mt*16 + c;
      float4 ov;
      ov.x = acc[mt][nt][0] + b4.x;
      ov.y = acc[mt][nt][1] + b4.y;
      ov.z = acc[mt][nt][2] + b4.z;
      ov.w = acc[mt][nt][3] + b4.w;
      *(float4*)(out + (size_t)m0*1024 + n0) = ov;
    }
  }
}

// ---------------- launch ----------------
extern "C" void kernel_launch(void* const* d_in, const int* in_sizes, int n_in,
                              void* d_out, int out_size, void* d_ws, size_t ws_size,
                              hipStream_t stream) {
  const float* x  = (const float*)d_in[0];
  const float* Wq = (const float*)d_in[1];
  const float* bq = (const float*)d_in[2];
  const float* Wk = (const float*)d_in[3];
  const float* bk = (const float*)d_in[4];
  const float* Wv = (const float*)d_in[5];
  const float* bv = (const float*)d_in[6];
  const float* Wo = (const float*)d_in[7];
  const float* bo = (const float*)d_in[8];

  char* ws = (char*)d_ws;
  const size_t MiB = 1u << 20;
  unsigned short* xbf = (unsigned short*)(ws);              // 8 MiB
  unsigned short* wqb = (unsigned short*)(ws +  8*MiB);     // 2 MiB
  unsigned short* wkb = (unsigned short*)(ws + 10*MiB);
  unsigned short* wvb = (unsigned short*)(ws + 12*MiB);
  unsigned short* wob = (unsigned short*)(ws + 14*MiB);
  bf16* Qb    = (bf16*)(ws + 16*MiB);                       // 8 MiB [B,H,S,DH]
  bf16* Kb    = (bf16*)(ws + 24*MiB);                       // 8 MiB [B,H,S,DH]
  bf16* VTb   = (bf16*)(ws + 32*MiB);                       // 8 MiB [B,H,DH,S]
  bf16* attnb = (bf16*)(ws + 40*MiB);                       // 8 MiB [M,E]

  convert_kernel<<<4096, 256, 0, stream>>>(x, Wq, Wk, Wv, Wo, xbf, wqb, wkb, wvb, wob);
  qkv_gemm<<<dim3(24, 32), 256, 0, stream>>>(
      (const bf16*)xbf, (const bf16*)wqb, (const bf16*)wkb, (const bf16*)wvb,
      bq, bk, bv, Qb, Kb, VTb);
  attn_kernel<<<dim3(32, 32), 256, 0, stream>>>(Qb, Kb, VTb, attnb);
  out_gemm<<<dim3(8, 32), 256, 0, stream>>>(attnb, (const bf16*)wob, bo, (float*)d_out);
}

// Round 8
// 227.711 us; speedup vs baseline: 1.0519x; 1.0231x over previous
//
#include <hip/hip_runtime.h>
#include <stdint.h>

// ---------------- problem constants ----------------
#define BB 2
#define SS 2048
#define EE 1024
#define HH 16
#define DHD 64
#define MM (BB*SS)          // 4096 tokens
// scale * log2(e): fold log2e into Q so softmax uses exp2 (v_exp_f32) directly
#define QSCALE (0.125f * 1.4426950408889634f)

typedef __bf16 bf16;
typedef __bf16 bf16x8 __attribute__((ext_vector_type(8)));
typedef __bf16 bf16x4 __attribute__((ext_vector_type(4)));
typedef float  f32x4  __attribute__((ext_vector_type(4)));
typedef unsigned short ushort8 __attribute__((ext_vector_type(8)));

#define MFMA16(a,b,c) __builtin_amdgcn_mfma_f32_16x16x32_bf16(a,b,c,0,0,0)

__device__ __forceinline__ void gload_lds16(const void* g, void* l) {
  __builtin_amdgcn_global_load_lds(
      (const __attribute__((address_space(1))) unsigned int*)g,
      (__attribute__((address_space(3))) unsigned int*)l, 16, 0, 0);
}

__device__ __forceinline__ unsigned short f2bf(float f) {
  union { float f; unsigned u; } v; v.f = f;
  return (unsigned short)((v.u + 0x7FFFu + ((v.u >> 16) & 1u)) >> 16);
}

// ---------------- kernel 0: fp32 -> bf16 conversion ----------------
__global__ void convert_kernel(const float* __restrict__ x,
                               const float* __restrict__ wq, const float* __restrict__ wk,
                               const float* __restrict__ wv, const float* __restrict__ wo,
                               unsigned short* __restrict__ xbf,
                               unsigned short* __restrict__ wqb, unsigned short* __restrict__ wkb,
                               unsigned short* __restrict__ wvb, unsigned short* __restrict__ wob) {
  long t = (long)blockIdx.x * blockDim.x + threadIdx.x;  // 1M threads
  long base = t * 8;
  const float* src; unsigned short* dst; long off;
  if (base < 4194304L) { src = x; dst = xbf; off = base; }
  else {
    long r = base - 4194304L; int j = (int)(r >> 20); off = r & 1048575L;
    src = (j==0)?wq:(j==1)?wk:(j==2)?wv:wo;
    dst = (j==0)?wqb:(j==1)?wkb:(j==2)?wvb:wob;
  }
  const float4* s4 = (const float4*)(src + off);
  float4 a = s4[0], b = s4[1];
  ushort8 o;
  o[0]=f2bf(a.x); o[1]=f2bf(a.y); o[2]=f2bf(a.z); o[3]=f2bf(a.w);
  o[4]=f2bf(b.x); o[5]=f2bf(b.y); o[6]=f2bf(b.z); o[7]=f2bf(b.w);
  *(ushort8*)(dst + off) = o;
}

// ---- shared GEMM K-loop: 3-buffer LDS, 2-deep prefetch, counted vmcnt ----
// SWAP=false: lane(c,g) reg r = C[m=g*4+r][n=c]
// SWAP=true : lane(c,g) reg r = C[m=c][n=g*4+r]  (wide C-stores along n)
#define GS_STAGE(kbuf, kt) { \
    const size_t kb_ = (size_t)(kt) * 64; \
    char* d_ = lds + (kbuf) * 16384 + tid * 16; \
    gload_lds16(a0 + kb_, d_); \
    gload_lds16(a1 + kb_, d_ + 4096); \
    gload_lds16(b0 + kb_, d_ + 8192); \
    gload_lds16(b1 + kb_, d_ + 12288); \
  }

template<bool SWAP>
__device__ __forceinline__ void gemm_kloop(
    const char* a0, const char* a1, const char* b0, const char* b1,
    char* lds, const int tid, const int (&aoff)[4], const int (&boff)[4],
    f32x4 (&acc)[4][4]) {
  GS_STAGE(0, 0);
  GS_STAGE(1, 1);
  int cur = 0;
  for (int kt = 0; kt < 32; ++kt) {
    if (kt < 30) {
      int sb = cur - 1; if (sb < 0) sb = 2;     // == (kt+2)%3, tile kt-1's buffer
      GS_STAGE(sb, kt + 2);
      asm volatile("s_waitcnt vmcnt(8)" ::: "memory");   // tile kt's 4 loads done
    } else if (kt == 30) {
      asm volatile("s_waitcnt vmcnt(4)" ::: "memory");
    } else {
      asm volatile("s_waitcnt vmcnt(0)" ::: "memory");
    }
    __builtin_amdgcn_s_barrier();
    const char* Ts = lds + cur * 16384;
    bf16x8 af[4], bfv[4];
#pragma unroll
    for (int mt=0; mt<4; ++mt) af[mt] = *(const bf16x8*)(Ts + aoff[mt]);
#pragma unroll
    for (int nt=0; nt<4; ++nt) bfv[nt] = *(const bf16x8*)(Ts + boff[nt]);
#pragma unroll
    for (int mt=0; mt<4; ++mt)
#pragma unroll
      for (int nt=0; nt<4; ++nt)
        acc[mt][nt] = SWAP ? MFMA16(bfv[nt], af[mt], acc[mt][nt])
                           : MFMA16(af[mt], bfv[nt], acc[mt][nt]);
    asm volatile("s_waitcnt lgkmcnt(0)" ::: "memory");   // my LDS reads retired
    __builtin_amdgcn_s_barrier();                        // safe to overwrite
    cur = (cur == 2) ? 0 : cur + 1;
  }
}

// ---------------- kernel 1: fused QKV projection GEMM ----------------
// C[m, n'] = x[m,:] . W[n,:] (+bias); proj = n'>>10 -> (Wq,Q)/(Wk,K)/(Wv,V^T)
__global__ __launch_bounds__(256) void qkv_gemm(
    const bf16* __restrict__ xbf,
    const bf16* __restrict__ wqb, const bf16* __restrict__ wkb, const bf16* __restrict__ wvb,
    const float* __restrict__ bq, const float* __restrict__ bk, const float* __restrict__ bv,
    bf16* __restrict__ Q, bf16* __restrict__ K, bf16* __restrict__ VT) {
  __shared__ char lds[49152] __attribute__((aligned(16)));
  const int tid = threadIdx.x;
  const int bm = blockIdx.y * 128;
  const int bnG = blockIdx.x * 128;
  const int proj = bnG >> 10;
  const int bn = bnG & 1023;
  const bf16* wsel = (proj==0)?wqb:(proj==1)?wkb:wvb;
  const float* bias = (proj==0)?bq:(proj==1)?bk:bv;

  const int lane = tid & 63, w = tid >> 6;
  const int wm = (w>>1)*64, wn = (w&1)*64;
  const int c = lane & 15, g = lane >> 4;

  const int sr = tid >> 2;
  const int scb = ((tid & 3) * 16) ^ ((sr & 3) << 4);
  const char* a0 = (const char*)xbf  + ((size_t)(bm + sr     ) * 1024) * 2 + scb;
  const char* a1 = (const char*)xbf  + ((size_t)(bm + 64 + sr) * 1024) * 2 + scb;
  const char* b0 = (const char*)wsel + ((size_t)(bn + sr     ) * 1024) * 2 + scb;
  const char* b1 = (const char*)wsel + ((size_t)(bn + 64 + sr) * 1024) * 2 + scb;

  int aoff[4], boff[4];
#pragma unroll
  for (int mt=0; mt<4; ++mt) { int rr = wm + mt*16 + c; aoff[mt] = rr*64 + ((g*16) ^ ((rr&3)<<4)); }
#pragma unroll
  for (int nt=0; nt<4; ++nt) { int rr = wn + nt*16 + c; boff[nt] = 8192 + rr*64 + ((g*16) ^ ((rr&3)<<4)); }

  f32x4 acc[4][4];
#pragma unroll
  for (int mt=0; mt<4; ++mt)
#pragma unroll
    for (int nt=0; nt<4; ++nt) acc[mt][nt] = (f32x4){0.f,0.f,0.f,0.f};

  const int bidx = bm >> 11;
  const int srow = bm & 2047;

  if (proj != 2) {
    gemm_kloop<true>(a0, a1, b0, b1, lds, tid, aoff, boff, acc);
    // lane(c,g) reg r = C[m = wm+mt*16+c][n = wn+nt*16+g*4+r]
    bf16* dst = (proj == 0) ? Q : K;
    const float qs = (proj == 0) ? QSCALE : 1.0f;
#pragma unroll
    for (int nt=0; nt<4; ++nt) {
      const int n0 = bn + wn + nt*16 + g*4;          // 4-aligned, within one head
      const float4 b4 = *(const float4*)(bias + n0);
      const int h = n0 >> 6, d0 = n0 & 63;
#pragma unroll
      for (int mt=0; mt<4; ++mt) {
        const int s = srow + wm + mt*16 + c;
        bf16x4 pk;
        pk[0] = (bf16)((acc[mt][nt][0] + b4.x) * qs);
        pk[1] = (bf16)((acc[mt][nt][1] + b4.y) * qs);
        pk[2] = (bf16)((acc[mt][nt][2] + b4.z) * qs);
        pk[3] = (bf16)((acc[mt][nt][3] + b4.w) * qs);
        *(bf16x4*)(dst + (((size_t)(bidx*16 + h))*2048 + s)*64 + d0) = pk;
      }
    }
  } else {
    gemm_kloop<false>(a0, a1, b0, b1, lds, tid, aoff, boff, acc);
    // lane(c,g) reg r = C[m = wm+mt*16+g*4+r][n = wn+nt*16+c]
#pragma unroll
    for (int nt=0; nt<4; ++nt) {
      const int n = bn + wn + nt*16 + c;
      const float bv_ = bias[n];
      const int h = n >> 6, d = n & 63;
#pragma unroll
      for (int mt=0; mt<4; ++mt) {
        const int m0 = wm + mt*16 + g*4;
        bf16x4 pk;
#pragma unroll
        for (int r=0;r<4;++r) pk[r] = (bf16)(acc[mt][nt][r] + bv_);
        *(bf16x4*)(VT + (((size_t)(bidx*16 + h))*64 + d)*2048 + (srow + m0)) = pk;
      }
    }
  }
}

// ---------------- kernel 2: flash attention (R4 version, verified 96us) ----------------
__global__ __launch_bounds__(256) void attn_kernel(
    const bf16* __restrict__ Q, const bf16* __restrict__ K,
    const bf16* __restrict__ VT, bf16* __restrict__ attn_out) {
  __shared__ char alds[32768] __attribute__((aligned(16)));
  const int tid = threadIdx.x;
  const int lane = tid & 63, w = tid >> 6;
  const int c = lane & 15, g = lane >> 4;
  const int x7 = c & 7;
  const int bh = blockIdx.y;                      // b*16 + h
  const int qb = blockIdx.x * 64 + w * 16;        // wave's q base
  const bf16* Qh = Q + (size_t)bh * 2048 * 64;
  const char* Khb = (const char*)(K  + (size_t)bh * 2048 * 64);
  const char* Vhb = (const char*)(VT + (size_t)bh * 64 * 2048);

  // staging: LDS(row, chunk) <- global(row, chunk ^ (row&7)); row=tid>>3, chunk=tid&7
  const int srow = tid >> 3, schunk = tid & 7;
  const int ssw = ((schunk ^ (srow & 7)) << 4);
  const char* srcK = Khb + (size_t)srow * 128  + ssw;
  const char* srcV = Vhb + (size_t)srow * 4096 + ssw;

#define ATT_STAGE(buf, kv) { \
    const char* sk_ = srcK + (size_t)(kv) * 128; \
    const char* sv_ = srcV + (size_t)(kv) * 2; \
    char* d_ = alds + (buf) * 16384 + tid * 16; \
    gload_lds16(sk_,            d_); \
    gload_lds16(sk_ + 32*128,   d_ + 4096); \
    gload_lds16(sv_,            d_ + 8192); \
    gload_lds16(sv_ + 32*4096,  d_ + 12288); \
  }

  // Q fragments (B-operand): lane holds q = qb+c, d = kk*32 + g*8 + j
  bf16x8 qf0 = *(const bf16x8*)(Qh + (size_t)(qb + c)*64 + g*8);
  bf16x8 qf1 = *(const bf16x8*)(Qh + (size_t)(qb + c)*64 + 32 + g*8);

  f32x4 o[4];
#pragma unroll
  for (int dt=0; dt<4; ++dt) o[dt] = (f32x4){0.f,0.f,0.f,0.f};
  float m = -1e30f, l = 0.f;

  ATT_STAGE(0, 0);
  for (int t = 0; t < 32; ++t) {
    const int cur = t & 1;
    if (t < 31) {
      ATT_STAGE(cur ^ 1, (t + 1) * 64);
      asm volatile("s_waitcnt vmcnt(4)" ::: "memory");
    } else {
      asm volatile("s_waitcnt vmcnt(0)" ::: "memory");
    }
    __builtin_amdgcn_s_barrier();

    const char* Kl = alds + cur * 16384;
    const char* Vl = Kl + 8192;

    // QK^T (swapped): st[ks] = scores for keys ks*16 + 4g + r, q = qb+c
    f32x4 st[4];
#pragma unroll
    for (int ks = 0; ks < 4; ++ks) {
      const char* kr = Kl + (ks*16 + c) * 128;
      bf16x8 k0 = *(const bf16x8*)(kr + (((g    ) ^ x7) << 4));
      bf16x8 k1 = *(const bf16x8*)(kr + (((g + 4) ^ x7) << 4));
      f32x4 z = (f32x4){0.f,0.f,0.f,0.f};
      z = MFMA16(k0, qf0, z);
      z = MFMA16(k1, qf1, z);
      st[ks] = z;
    }

    // online softmax over 64 keys (scores in log2 domain via QSCALE)
    float tmax = -1e30f;
#pragma unroll
    for (int ks = 0; ks < 4; ++ks)
      tmax = fmaxf(tmax, fmaxf(fmaxf(st[ks][0], st[ks][1]), fmaxf(st[ks][2], st[ks][3])));
    tmax = fmaxf(tmax, __shfl_xor(tmax, 16, 64));
    tmax = fmaxf(tmax, __shfl_xor(tmax, 32, 64));
    const float mnew = fmaxf(m, tmax);
    const float corr = __builtin_exp2f(m - mnew);
    float p[4][4]; float ps = 0.f;
#pragma unroll
    for (int ks = 0; ks < 4; ++ks)
#pragma unroll
      for (int r = 0; r < 4; ++r) { p[ks][r] = __builtin_exp2f(st[ks][r] - mnew); ps += p[ks][r]; }
    ps += __shfl_xor(ps, 16, 64);
    ps += __shfl_xor(ps, 32, 64);
    l = l * corr + ps;
    m = mnew;
#pragma unroll
    for (int dt=0; dt<4; ++dt) o[dt] *= corr;

    // P fragments, permuted-k (lane-local): slot (g,j<4) = key 4g+j (+16 for j>=4)
    bf16x8 pfA, pfB;
#pragma unroll
    for (int r = 0; r < 4; ++r) {
      pfA[r] = (bf16)p[0][r]; pfA[4+r] = (bf16)p[1][r];
      pfB[r] = (bf16)p[2][r]; pfB[4+r] = (bf16)p[3][r];
    }

    // PV: O^T[d][q] += V^T[d][key]*P^T[key][q]; V read with same key permutation
#pragma unroll
    for (int dt = 0; dt < 4; ++dt) {
      const char* vr = Vl + (dt*16 + c) * 128;
      const int i8 = (g & 1) * 8, gh = g >> 1;
      bf16x4 va0 = *(const bf16x4*)(vr + (((gh    ) ^ x7) << 4) + i8);   // keys  4g..
      bf16x4 va1 = *(const bf16x4*)(vr + (((gh + 2) ^ x7) << 4) + i8);   // keys 16+4g..
      bf16x4 vb0 = *(const bf16x4*)(vr + (((gh + 4) ^ x7) << 4) + i8);   // keys 32+4g..
      bf16x4 vb1 = *(const bf16x4*)(vr + (((gh + 6) ^ x7) << 4) + i8);   // keys 48+4g..
      bf16x8 vfA = __builtin_shufflevector(va0, va1, 0,1,2,3,4,5,6,7);
      bf16x8 vfB = __builtin_shufflevector(vb0, vb1, 0,1,2,3,4,5,6,7);
      o[dt] = MFMA16(vfA, pfA, o[dt]);
      o[dt] = MFMA16(vfB, pfB, o[dt]);
    }

    asm volatile("s_waitcnt lgkmcnt(0)" ::: "memory");
    __builtin_amdgcn_s_barrier();
  }
#undef ATT_STAGE

  const float inv = 1.0f / l;
  const int srow_q = qb + c;
  const int b = bh >> 4, h = bh & 15;
  bf16* outrow = attn_out + ((size_t)(b*2048 + srow_q))*1024 + h*64;
#pragma unroll
  for (int dt=0; dt<4; ++dt) {
    bf16x4 ov;
#pragma unroll
    for (int r=0;r<4;++r) ov[r] = (bf16)(o[dt][r] * inv);
    *(bf16x4*)(outrow + dt*16 + g*4) = ov;
  }
}

// ---------------- kernel 3: output projection GEMM ----------------
// 64x128 tile (grid 8x64 = 512 blocks = 2/CU), 4 waves each 64x32,
// 3-buffer LDS 2-deep prefetch, SWAP orientation -> float4 stores.
__global__ __launch_bounds__(256) void out_gemm(
    const bf16* __restrict__ A, const bf16* __restrict__ W,
    const float* __restrict__ bias, float* __restrict__ out) {
  __shared__ char lds[36864] __attribute__((aligned(16)));
  const int tid = threadIdx.x;
  const int bm = blockIdx.y * 64, bn = blockIdx.x * 128;
  const int lane = tid & 63, w = tid >> 6;
  const int c = lane & 15, g = lane >> 4;

  const int sr = tid >> 2;                       // 0..63
  const int scb = ((tid & 3) * 16) ^ ((sr & 3) << 4);
  const char* a0 = (const char*)A + ((size_t)(bm + sr     ) * 1024) * 2 + scb;
  const char* b0 = (const char*)W + ((size_t)(bn + sr     ) * 1024) * 2 + scb;
  const char* b1 = (const char*)W + ((size_t)(bn + 64 + sr) * 1024) * 2 + scb;

#define OUT_STAGE(kbuf, kt) { \
    const size_t kb_ = (size_t)(kt) * 64; \
    char* d_ = lds + (kbuf) * 12288 + tid * 16; \
    gload_lds16(a0 + kb_, d_); \
    gload_lds16(b0 + kb_, d_ + 4096); \
    gload_lds16(b1 + kb_, d_ + 8192); \
  }

  int aoff[4], boff[2];
#pragma unroll
  for (int mt=0; mt<4; ++mt) { int rr = mt*16 + c; aoff[mt] = rr*64 + ((g*16) ^ ((rr&3)<<4)); }
#pragma unroll
  for (int nt=0; nt<2; ++nt) { int rr = w*32 + nt*16 + c; boff[nt] = 4096 + rr*64 + ((g*16) ^ ((rr&3)<<4)); }

  f32x4 acc[4][2];
#pragma unroll
  for (int mt=0; mt<4; ++mt)
#pragma unroll
    for (int nt=0; nt<2; ++nt) acc[mt][nt] = (f32x4){0.f,0.f,0.f,0.f};

  OUT_STAGE(0, 0);
  OUT_STAGE(1, 1);
  int cur = 0;
  for (int kt = 0; kt < 32; ++kt) {
    if (kt < 30) {
      int sb = cur - 1; if (sb < 0) sb = 2;
      OUT_STAGE(sb, kt + 2);
      asm volatile("s_waitcnt vmcnt(6)" ::: "memory");   // tile kt's 3 loads done
    } else if (kt == 30) {
      asm volatile("s_waitcnt vmcnt(3)" ::: "memory");
    } else {
      asm volatile("s_waitcnt vmcnt(0)" ::: "memory");
    }
    __builtin_amdgcn_s_barrier();
    const char* Ts = lds + cur * 12288;
    bf16x8 af[4], bfv[2];
#pragma unroll
    for (int mt=0; mt<4; ++mt) af[mt] = *(const bf16x8*)(Ts + aoff[mt]);
#pragma unroll
    for (int nt=0; nt<2; ++nt) bfv[nt] = *(const bf16x8*)(Ts + boff[nt]);
#pragma unroll
    for (int mt=0; mt<4; ++mt)
#pragma unroll
      for (int nt=0; nt<2; ++nt)
        acc[mt][nt] = MFMA16(bfv[nt], af[mt], acc[mt][nt]);   // SWAP orientation
    asm volatile("s_waitcnt lgkmcnt(0)" ::: "memory");
    __builtin_amdgcn_s_barrier();
    cur = (cur == 2) ? 0 : cur + 1;
  }
#undef OUT_STAGE

  // lane(c,g) reg r = C[m = bm+mt*16+c][n = bn+w*32+nt*16+g*4+r] -> float4 store
#pragma unroll
  for (int nt=0; nt<2; ++nt) {
    const int n0 = bn + w*32 + nt*16 + g*4;
    const float4 b4 = *(const float4*)(bias + n0);
#pragma unroll
    for (int mt=0; mt<4; ++mt) {
      const int m0 = bm + mt*16 + c;
      float4 ov;
      ov.x = acc[mt][nt][0] + b4.x;
      ov.y = acc[mt][nt][1] + b4.y;
      ov.z = acc[mt][nt][2] + b4.z;
      ov.w = acc[mt][nt][3] + b4.w;
      *(float4*)(out + (size_t)m0*1024 + n0) = ov;
    }
  }
}

// ---------------- launch ----------------
extern "C" void kernel_launch(void* const* d_in, const int* in_sizes, int n_in,
                              void* d_out, int out_size, void* d_ws, size_t ws_size,
                              hipStream_t stream) {
  const float* x  = (const float*)d_in[0];
  const float* Wq = (const float*)d_in[1];
  const float* bq = (const float*)d_in[2];
  const float* Wk = (const float*)d_in[3];
  const float* bk = (const float*)d_in[4];
  const float* Wv = (const float*)d_in[5];
  const float* bv = (const float*)d_in[6];
  const float* Wo = (const float*)d_in[7];
  const float* bo = (const float*)d_in[8];

  char* ws = (char*)d_ws;
  const size_t MiB = 1u << 20;
  unsigned short* xbf = (unsigned short*)(ws);              // 8 MiB
  unsigned short* wqb = (unsigned short*)(ws +  8*MiB);     // 2 MiB
  unsigned short* wkb = (unsigned short*)(ws + 10*MiB);
  unsigned short* wvb = (unsigned short*)(ws + 12*MiB);
  unsigned short* wob = (unsigned short*)(ws + 14*MiB);
  bf16* Qb    = (bf16*)(ws + 16*MiB);                       // 8 MiB [B,H,S,DH]
  bf16* Kb    = (bf16*)(ws + 24*MiB);                       // 8 MiB [B,H,S,DH]
  bf16* VTb   = (bf16*)(ws + 32*MiB);                       // 8 MiB [B,H,DH,S]
  bf16* attnb = (bf16*)(ws + 40*MiB);                       // 8 MiB [M,E]

  convert_kernel<<<4096, 256, 0, stream>>>(x, Wq, Wk, Wv, Wo, xbf, wqb, wkb, wvb, wob);
  qkv_gemm<<<dim3(24, 32), 256, 0, stream>>>(
      (const bf16*)xbf, (const bf16*)wqb, (const bf16*)wkb, (const bf16*)wvb,
      bq, bk, bv, Qb, Kb, VTb);
  attn_kernel<<<dim3(32, 32), 256, 0, stream>>>(Qb, Kb, VTb, attnb);
  out_gemm<<<dim3(8, 64), 256, 0, stream>>>(attnb, (const bf16*)wob, bo, (float*)d_out);
}

// Round 9
// 224.838 us; speedup vs baseline: 1.0653x; 1.0128x over previous
//
#include <hip/hip_runtime.h>
#include <stdint.h>

// ---------------- problem constants ----------------
#define BB 2
#define SS 2048
#define EE 1024
#define HH 16
#define DHD 64
#define MM (BB*SS)          // 4096 tokens
// scale * log2(e): fold log2e into Q so softmax uses exp2 (v_exp_f32) directly
#define QSCALE (0.125f * 1.4426950408889634f)

typedef __bf16 bf16;
typedef __bf16 bf16x8 __attribute__((ext_vector_type(8)));
typedef __bf16 bf16x4 __attribute__((ext_vector_type(4)));
typedef float  f32x4  __attribute__((ext_vector_type(4)));
typedef unsigned short ushort8 __attribute__((ext_vector_type(8)));

#define MFMA16(a,b,c) __builtin_amdgcn_mfma_f32_16x16x32_bf16(a,b,c,0,0,0)

__device__ __forceinline__ void gload_lds16(const void* g, void* l) {
  __builtin_amdgcn_global_load_lds(
      (const __attribute__((address_space(1))) unsigned int*)g,
      (__attribute__((address_space(3))) unsigned int*)l, 16, 0, 0);
}

__device__ __forceinline__ unsigned short f2bf(float f) {
  union { float f; unsigned u; } v; v.f = f;
  return (unsigned short)((v.u + 0x7FFFu + ((v.u >> 16) & 1u)) >> 16);
}

// ---------------- kernel 0: fp32 -> bf16 conversion ----------------
__global__ void convert_kernel(const float* __restrict__ x,
                               const float* __restrict__ wq, const float* __restrict__ wk,
                               const float* __restrict__ wv, const float* __restrict__ wo,
                               unsigned short* __restrict__ xbf,
                               unsigned short* __restrict__ wqb, unsigned short* __restrict__ wkb,
                               unsigned short* __restrict__ wvb, unsigned short* __restrict__ wob) {
  long t = (long)blockIdx.x * blockDim.x + threadIdx.x;  // 1M threads
  long base = t * 8;
  const float* src; unsigned short* dst; long off;
  if (base < 4194304L) { src = x; dst = xbf; off = base; }
  else {
    long r = base - 4194304L; int j = (int)(r >> 20); off = r & 1048575L;
    src = (j==0)?wq:(j==1)?wk:(j==2)?wv:wo;
    dst = (j==0)?wqb:(j==1)?wkb:(j==2)?wvb:wob;
  }
  const float4* s4 = (const float4*)(src + off);
  float4 a = s4[0], b = s4[1];
  ushort8 o;
  o[0]=f2bf(a.x); o[1]=f2bf(a.y); o[2]=f2bf(a.z); o[3]=f2bf(a.w);
  o[4]=f2bf(b.x); o[5]=f2bf(b.y); o[6]=f2bf(b.z); o[7]=f2bf(b.w);
  *(ushort8*)(dst + off) = o;
}

// ---- shared GEMM K-loop: 3-buffer LDS, 2-deep prefetch, SINGLE barrier ----
// body(t): vmcnt(4) [all waves' stage(t) complete] ; barrier ;
//          stage(t+2) ; ds_read buf[t%3] ; MFMA.
// Overwrite hazard: stage(t+2) targets buf[(t-1)%3]; every wave's reads of it
// (at body t-1) completed before that wave's MFMAs, hence before barrier(t).
#define GS_STAGE(kbuf, kt) { \
    const size_t kb_ = (size_t)(kt) * 64; \
    char* d_ = lds + (kbuf) * 16384 + tid * 16; \
    gload_lds16(a0 + kb_, d_); \
    gload_lds16(a1 + kb_, d_ + 4096); \
    gload_lds16(b0 + kb_, d_ + 8192); \
    gload_lds16(b1 + kb_, d_ + 12288); \
  }

template<bool SWAP>
__device__ __forceinline__ void gemm_kloop(
    const char* a0, const char* a1, const char* b0, const char* b1,
    char* lds, const int tid, const int (&aoff)[4], const int (&boff)[4],
    f32x4 (&acc)[4][4]) {
  GS_STAGE(0, 0);
  GS_STAGE(1, 1);
  int cur = 0;
  for (int kt = 0; kt < 32; ++kt) {
    if (kt < 31) {
      asm volatile("s_waitcnt vmcnt(4)" ::: "memory");   // stage(kt) done (all waves after barrier)
    } else {
      asm volatile("s_waitcnt vmcnt(0)" ::: "memory");
    }
    __builtin_amdgcn_s_barrier();
    if (kt < 30) {
      int sb = cur + 2; if (sb >= 3) sb -= 3;
      GS_STAGE(sb, kt + 2);
    }
    const char* Ts = lds + cur * 16384;
    bf16x8 af[4], bfv[4];
#pragma unroll
    for (int mt=0; mt<4; ++mt) af[mt] = *(const bf16x8*)(Ts + aoff[mt]);
#pragma unroll
    for (int nt=0; nt<4; ++nt) bfv[nt] = *(const bf16x8*)(Ts + boff[nt]);
#pragma unroll
    for (int mt=0; mt<4; ++mt)
#pragma unroll
      for (int nt=0; nt<4; ++nt)
        acc[mt][nt] = SWAP ? MFMA16(bfv[nt], af[mt], acc[mt][nt])
                           : MFMA16(af[mt], bfv[nt], acc[mt][nt]);
    cur = (cur == 2) ? 0 : cur + 1;
  }
}

// ---------------- kernel 1: fused QKV projection GEMM ----------------
// C[m, n'] = x[m,:] . W[n,:] (+bias); proj = n'>>10 -> (Wq,Q)/(Wk,K)/(Wv,V^T)
__global__ __launch_bounds__(256) void qkv_gemm(
    const bf16* __restrict__ xbf,
    const bf16* __restrict__ wqb, const bf16* __restrict__ wkb, const bf16* __restrict__ wvb,
    const float* __restrict__ bq, const float* __restrict__ bk, const float* __restrict__ bv,
    bf16* __restrict__ Q, bf16* __restrict__ K, bf16* __restrict__ VT) {
  __shared__ char lds[49152] __attribute__((aligned(16)));
  const int tid = threadIdx.x;
  const int bm = blockIdx.y * 128;
  const int bnG = blockIdx.x * 128;
  const int proj = bnG >> 10;
  const int bn = bnG & 1023;
  const bf16* wsel = (proj==0)?wqb:(proj==1)?wkb:wvb;
  const float* bias = (proj==0)?bq:(proj==1)?bk:bv;

  const int lane = tid & 63, w = tid >> 6;
  const int wm = (w>>1)*64, wn = (w&1)*64;
  const int c = lane & 15, g = lane >> 4;

  const int sr = tid >> 2;
  const int scb = ((tid & 3) * 16) ^ ((sr & 3) << 4);
  const char* a0 = (const char*)xbf  + ((size_t)(bm + sr     ) * 1024) * 2 + scb;
  const char* a1 = (const char*)xbf  + ((size_t)(bm + 64 + sr) * 1024) * 2 + scb;
  const char* b0 = (const char*)wsel + ((size_t)(bn + sr     ) * 1024) * 2 + scb;
  const char* b1 = (const char*)wsel + ((size_t)(bn + 64 + sr) * 1024) * 2 + scb;

  int aoff[4], boff[4];
#pragma unroll
  for (int mt=0; mt<4; ++mt) { int rr = wm + mt*16 + c; aoff[mt] = rr*64 + ((g*16) ^ ((rr&3)<<4)); }
#pragma unroll
  for (int nt=0; nt<4; ++nt) { int rr = wn + nt*16 + c; boff[nt] = 8192 + rr*64 + ((g*16) ^ ((rr&3)<<4)); }

  f32x4 acc[4][4];
#pragma unroll
  for (int mt=0; mt<4; ++mt)
#pragma unroll
    for (int nt=0; nt<4; ++nt) acc[mt][nt] = (f32x4){0.f,0.f,0.f,0.f};

  const int bidx = bm >> 11;
  const int srow = bm & 2047;

  if (proj != 2) {
    gemm_kloop<true>(a0, a1, b0, b1, lds, tid, aoff, boff, acc);
    // lane(c,g) reg r = C[m = wm+mt*16+c][n = wn+nt*16+g*4+r]
    bf16* dst = (proj == 0) ? Q : K;
    const float qs = (proj == 0) ? QSCALE : 1.0f;
#pragma unroll
    for (int nt=0; nt<4; ++nt) {
      const int n0 = bn + wn + nt*16 + g*4;          // 4-aligned, within one head
      const float4 b4 = *(const float4*)(bias + n0);
      const int h = n0 >> 6, d0 = n0 & 63;
#pragma unroll
      for (int mt=0; mt<4; ++mt) {
        const int s = srow + wm + mt*16 + c;
        bf16x4 pk;
        pk[0] = (bf16)((acc[mt][nt][0] + b4.x) * qs);
        pk[1] = (bf16)((acc[mt][nt][1] + b4.y) * qs);
        pk[2] = (bf16)((acc[mt][nt][2] + b4.z) * qs);
        pk[3] = (bf16)((acc[mt][nt][3] + b4.w) * qs);
        *(bf16x4*)(dst + (((size_t)(bidx*16 + h))*2048 + s)*64 + d0) = pk;
      }
    }
  } else {
    gemm_kloop<false>(a0, a1, b0, b1, lds, tid, aoff, boff, acc);
    // lane(c,g) reg r = C[m = wm+mt*16+g*4+r][n = wn+nt*16+c]
#pragma unroll
    for (int nt=0; nt<4; ++nt) {
      const int n = bn + wn + nt*16 + c;
      const float bv_ = bias[n];
      const int h = n >> 6, d = n & 63;
#pragma unroll
      for (int mt=0; mt<4; ++mt) {
        const int m0 = wm + mt*16 + g*4;
        bf16x4 pk;
#pragma unroll
        for (int r=0;r<4;++r) pk[r] = (bf16)(acc[mt][nt][r] + bv_);
        *(bf16x4*)(VT + (((size_t)(bidx*16 + h))*64 + d)*2048 + (srow + m0)) = pk;
      }
    }
  }
}

// ---------------- kernel 2: flash attention (single-barrier + lean defer-max) ----------------
// grid = (S/64, B*H), 4 waves/block, wave owns 16 q-rows. KVBLK=64.
// body(t): STAGE(t+1); compute(t); vmcnt(0); barrier.
// Overwrite hazard: STAGE at body(t+1) hits buf used at body(t); every wave's
// LDS reads completed before its MFMAs, hence before barrier(t).
__global__ __launch_bounds__(256) void attn_kernel(
    const bf16* __restrict__ Q, const bf16* __restrict__ K,
    const bf16* __restrict__ VT, bf16* __restrict__ attn_out) {
  __shared__ char alds[32768] __attribute__((aligned(16)));
  const int tid = threadIdx.x;
  const int lane = tid & 63, w = tid >> 6;
  const int c = lane & 15, g = lane >> 4;
  const int x7 = c & 7;
  const int bh = blockIdx.y;                      // b*16 + h
  const int qb = blockIdx.x * 64 + w * 16;        // wave's q base
  const bf16* Qh = Q + (size_t)bh * 2048 * 64;
  const char* Khb = (const char*)(K  + (size_t)bh * 2048 * 64);
  const char* Vhb = (const char*)(VT + (size_t)bh * 64 * 2048);

  // staging: LDS(row, chunk) <- global(row, chunk ^ (row&7)); row=tid>>3, chunk=tid&7
  const int srow = tid >> 3, schunk = tid & 7;
  const int ssw = ((schunk ^ (srow & 7)) << 4);
  const char* srcK = Khb + (size_t)srow * 128  + ssw;
  const char* srcV = Vhb + (size_t)srow * 4096 + ssw;

#define ATT_STAGE(buf, kv) { \
    const char* sk_ = srcK + (size_t)(kv) * 128; \
    const char* sv_ = srcV + (size_t)(kv) * 2; \
    char* d_ = alds + (buf) * 16384 + tid * 16; \
    gload_lds16(sk_,            d_); \
    gload_lds16(sk_ + 32*128,   d_ + 4096); \
    gload_lds16(sv_,            d_ + 8192); \
    gload_lds16(sv_ + 32*4096,  d_ + 12288); \
  }

  // Q fragments (B-operand): lane holds q = qb+c, d = kk*32 + g*8 + j
  bf16x8 qf0 = *(const bf16x8*)(Qh + (size_t)(qb + c)*64 + g*8);
  bf16x8 qf1 = *(const bf16x8*)(Qh + (size_t)(qb + c)*64 + 32 + g*8);

  f32x4 o[4];
#pragma unroll
  for (int dt=0; dt<4; ++dt) o[dt] = (f32x4){0.f,0.f,0.f,0.f};
  float m = -1e30f, l = 0.f;

  ATT_STAGE(0, 0);
  asm volatile("s_waitcnt vmcnt(0)" ::: "memory");
  __builtin_amdgcn_s_barrier();

  for (int t = 0; t < 32; ++t) {
    const int cur = t & 1;
    if (t < 31) ATT_STAGE(cur ^ 1, (t + 1) * 64);

    const char* Kl = alds + cur * 16384;
    const char* Vl = Kl + 8192;

    // QK^T (swapped): st[ks] = scores for keys ks*16 + 4g + r, q = qb+c
    f32x4 st[4];
#pragma unroll
    for (int ks = 0; ks < 4; ++ks) {
      const char* kr = Kl + (ks*16 + c) * 128;
      bf16x8 k0 = *(const bf16x8*)(kr + (((g    ) ^ x7) << 4));
      bf16x8 k1 = *(const bf16x8*)(kr + (((g + 4) ^ x7) << 4));
      f32x4 z = (f32x4){0.f,0.f,0.f,0.f};
      z = MFMA16(k0, qf0, z);
      z = MFMA16(k1, qf1, z);
      st[ks] = z;
    }

    // online softmax over 64 keys (log2 domain); lean defer-max (THR=8):
    // skip the rescale (1 exp2 + 17 mul) unless the tile max grew past m+8.
    float tmax = -1e30f;
#pragma unroll
    for (int ks = 0; ks < 4; ++ks)
      tmax = fmaxf(tmax, fmaxf(fmaxf(st[ks][0], st[ks][1]), fmaxf(st[ks][2], st[ks][3])));
    tmax = fmaxf(tmax, __shfl_xor(tmax, 16, 64));
    tmax = fmaxf(tmax, __shfl_xor(tmax, 32, 64));
    if (!__all(tmax <= m + 8.f)) {       // wave-uniform (m, tmax uniform)
      const float mnew = fmaxf(m, tmax);
      const float corr = __builtin_exp2f(m - mnew);
      l *= corr;
#pragma unroll
      for (int dt=0; dt<4; ++dt) o[dt] *= corr;
      m = mnew;
    }
    float p[4][4]; float ps = 0.f;
#pragma unroll
    for (int ks = 0; ks < 4; ++ks)
#pragma unroll
      for (int r = 0; r < 4; ++r) { p[ks][r] = __builtin_exp2f(st[ks][r] - m); ps += p[ks][r]; }
    ps += __shfl_xor(ps, 16, 64);
    ps += __shfl_xor(ps, 32, 64);
    l += ps;

    // P fragments, permuted-k (lane-local): slot (g,j<4) = key 4g+j (+16 for j>=4)
    bf16x8 pfA, pfB;
#pragma unroll
    for (int r = 0; r < 4; ++r) {
      pfA[r] = (bf16)p[0][r]; pfA[4+r] = (bf16)p[1][r];
      pfB[r] = (bf16)p[2][r]; pfB[4+r] = (bf16)p[3][r];
    }

    // PV: O^T[d][q] += V^T[d][key]*P^T[key][q]; V read with same key permutation
#pragma unroll
    for (int dt = 0; dt < 4; ++dt) {
      const char* vr = Vl + (dt*16 + c) * 128;
      const int i8 = (g & 1) * 8, gh = g >> 1;
      bf16x4 va0 = *(const bf16x4*)(vr + (((gh    ) ^ x7) << 4) + i8);   // keys  4g..
      bf16x4 va1 = *(const bf16x4*)(vr + (((gh + 2) ^ x7) << 4) + i8);   // keys 16+4g..
      bf16x4 vb0 = *(const bf16x4*)(vr + (((gh + 4) ^ x7) << 4) + i8);   // keys 32+4g..
      bf16x4 vb1 = *(const bf16x4*)(vr + (((gh + 6) ^ x7) << 4) + i8);   // keys 48+4g..
      bf16x8 vfA = __builtin_shufflevector(va0, va1, 0,1,2,3,4,5,6,7);
      bf16x8 vfB = __builtin_shufflevector(vb0, vb1, 0,1,2,3,4,5,6,7);
      o[dt] = MFMA16(vfA, pfA, o[dt]);
      o[dt] = MFMA16(vfB, pfB, o[dt]);
    }

    if (t < 31) {
      asm volatile("s_waitcnt vmcnt(0)" ::: "memory");   // stage(t+1) landed
      __builtin_amdgcn_s_barrier();                      // one barrier per iter
    }
  }
#undef ATT_STAGE

  const float inv = 1.0f / l;
  const int srow_q = qb + c;
  const int b = bh >> 4, h = bh & 15;
  bf16* outrow = attn_out + ((size_t)(b*2048 + srow_q))*1024 + h*64;
#pragma unroll
  for (int dt=0; dt<4; ++dt) {
    bf16x4 ov;
#pragma unroll
    for (int r=0;r<4;++r) ov[r] = (bf16)(o[dt][r] * inv);
    *(bf16x4*)(outrow + dt*16 + g*4) = ov;
  }
}

// ---------------- kernel 3: output projection GEMM ----------------
// 64x128 tile (grid 8x64 = 512 blocks = 2/CU), 3-buffer single-barrier loop,
// SWAP orientation -> float4 stores.
__global__ __launch_bounds__(256) void out_gemm(
    const bf16* __restrict__ A, const bf16* __restrict__ W,
    const float* __restrict__ bias, float* __restrict__ out) {
  __shared__ char lds[36864] __attribute__((aligned(16)));
  const int tid = threadIdx.x;
  const int bm = blockIdx.y * 64, bn = blockIdx.x * 128;
  const int lane = tid & 63, w = tid >> 6;
  const int c = lane & 15, g = lane >> 4;

  const int sr = tid >> 2;                       // 0..63
  const int scb = ((tid & 3) * 16) ^ ((sr & 3) << 4);
  const char* a0 = (const char*)A + ((size_t)(bm + sr     ) * 1024) * 2 + scb;
  const char* b0 = (const char*)W + ((size_t)(bn + sr     ) * 1024) * 2 + scb;
  const char* b1 = (const char*)W + ((size_t)(bn + 64 + sr) * 1024) * 2 + scb;

#define OUT_STAGE(kbuf, kt) { \
    const size_t kb_ = (size_t)(kt) * 64; \
    char* d_ = lds + (kbuf) * 12288 + tid * 16; \
    gload_lds16(a0 + kb_, d_); \
    gload_lds16(b0 + kb_, d_ + 4096); \
    gload_lds16(b1 + kb_, d_ + 8192); \
  }

  int aoff[4], boff[2];
#pragma unroll
  for (int mt=0; mt<4; ++mt) { int rr = mt*16 + c; aoff[mt] = rr*64 + ((g*16) ^ ((rr&3)<<4)); }
#pragma unroll
  for (int nt=0; nt<2; ++nt) { int rr = w*32 + nt*16 + c; boff[nt] = 4096 + rr*64 + ((g*16) ^ ((rr&3)<<4)); }

  f32x4 acc[4][2];
#pragma unroll
  for (int mt=0; mt<4; ++mt)
#pragma unroll
    for (int nt=0; nt<2; ++nt) acc[mt][nt] = (f32x4){0.f,0.f,0.f,0.f};

  OUT_STAGE(0, 0);
  OUT_STAGE(1, 1);
  int cur = 0;
  for (int kt = 0; kt < 32; ++kt) {
    if (kt < 31) {
      asm volatile("s_waitcnt vmcnt(3)" ::: "memory");   // stage(kt) done
    } else {
      asm volatile("s_waitcnt vmcnt(0)" ::: "memory");
    }
    __builtin_amdgcn_s_barrier();
    if (kt < 30) {
      int sb = cur + 2; if (sb >= 3) sb -= 3;
      OUT_STAGE(sb, kt + 2);
    }
    const char* Ts = lds + cur * 12288;
    bf16x8 af[4], bfv[2];
#pragma unroll
    for (int mt=0; mt<4; ++mt) af[mt] = *(const bf16x8*)(Ts + aoff[mt]);
#pragma unroll
    for (int nt=0; nt<2; ++nt) bfv[nt] = *(const bf16x8*)(Ts + boff[nt]);
#pragma unroll
    for (int mt=0; mt<4; ++mt)
#pragma unroll
      for (int nt=0; nt<2; ++nt)
        acc[mt][nt] = MFMA16(bfv[nt], af[mt], acc[mt][nt]);   // SWAP orientation
    cur = (cur == 2) ? 0 : cur + 1;
  }
#undef OUT_STAGE

  // lane(c,g) reg r = C[m = bm+mt*16+c][n = bn+w*32+nt*16+g*4+r] -> float4 store
#pragma unroll
  for (int nt=0; nt<2; ++nt) {
    const int n0 = bn + w*32 + nt*16 + g*4;
    const float4 b4 = *(const float4*)(bias + n0);
#pragma unroll
    for (int mt=0; mt<4; ++mt) {
      const int m0 = bm + mt*16 + c;
      float4 ov;
      ov.x = acc[mt][nt][0] + b4.x;
      ov.y = acc[mt][nt][1] + b4.y;
      ov.z = acc[mt][nt][2] + b4.z;
      ov.w = acc[mt][nt][3] + b4.w;
      *(float4*)(out + (size_t)m0*1024 + n0) = ov;
    }
  }
}

// ---------------- launch ----------------
extern "C" void kernel_launch(void* const* d_in, const int* in_sizes, int n_in,
                              void* d_out, int out_size, void* d_ws, size_t ws_size,
                              hipStream_t stream) {
  const float* x  = (const float*)d_in[0];
  const float* Wq = (const float*)d_in[1];
  const float* bq = (const float*)d_in[2];
  const float* Wk = (const float*)d_in[3];
  const float* bk = (const float*)d_in[4];
  const float* Wv = (const float*)d_in[5];
  const float* bv = (const float*)d_in[6];
  const float* Wo = (const float*)d_in[7];
  const float* bo = (const float*)d_in[8];

  char* ws = (char*)d_ws;
  const size_t MiB = 1u << 20;
  unsigned short* xbf = (unsigned short*)(ws);              // 8 MiB
  unsigned short* wqb = (unsigned short*)(ws +  8*MiB);     // 2 MiB
  unsigned short* wkb = (unsigned short*)(ws + 10*MiB);
  unsigned short* wvb = (unsigned short*)(ws + 12*MiB);
  unsigned short* wob = (unsigned short*)(ws + 14*MiB);
  bf16* Qb    = (bf16*)(ws + 16*MiB);                       // 8 MiB [B,H,S,DH]
  bf16* Kb    = (bf16*)(ws + 24*MiB);                       // 8 MiB [B,H,S,DH]
  bf16* VTb   = (bf16*)(ws + 32*MiB);                       // 8 MiB [B,H,DH,S]
  bf16* attnb = (bf16*)(ws + 40*MiB);                       // 8 MiB [M,E]

  convert_kernel<<<4096, 256, 0, stream>>>(x, Wq, Wk, Wv, Wo, xbf, wqb, wkb, wvb, wob);
  qkv_gemm<<<dim3(24, 32), 256, 0, stream>>>(
      (const bf16*)xbf, (const bf16*)wqb, (const bf16*)wkb, (const bf16*)wvb,
      bq, bk, bv, Qb, Kb, VTb);
  attn_kernel<<<dim3(32, 32), 256, 0, stream>>>(Qb, Kb, VTb, attnb);
  out_gemm<<<dim3(8, 64), 256, 0, stream>>>(attnb, (const bf16*)wob, bo, (float*)d_out);
}

// Round 10
// 203.442 us; speedup vs baseline: 1.1773x; 1.1052x over previous
//
#include <hip/hip_runtime.h>
#include <stdint.h>

// ---------------- problem constants ----------------
#define BB 2
#define SS 2048
#define EE 1024
#define HH 16
#define DHD 64
#define MM (BB*SS)          // 4096 tokens
// scale * log2(e): fold log2e into Q so softmax uses exp2 (v_exp_f32) directly
#define QSCALE (0.125f * 1.4426950408889634f)

typedef __bf16 bf16;
typedef __bf16 bf16x8 __attribute__((ext_vector_type(8)));
typedef __bf16 bf16x4 __attribute__((ext_vector_type(4)));
typedef __bf16 bf16x2 __attribute__((ext_vector_type(2)));
typedef float  f32x4  __attribute__((ext_vector_type(4)));
typedef float  f32x16 __attribute__((ext_vector_type(16)));
typedef unsigned short ushort8 __attribute__((ext_vector_type(8)));

#define MFMA16(a,b,c) __builtin_amdgcn_mfma_f32_16x16x32_bf16(a,b,c,0,0,0)
#define MFMA32(a,b,c) __builtin_amdgcn_mfma_f32_32x32x16_bf16(a,b,c,0,0,0)

__device__ __forceinline__ void gload_lds16(const void* g, void* l) {
  __builtin_amdgcn_global_load_lds(
      (const __attribute__((address_space(1))) unsigned int*)g,
      (__attribute__((address_space(3))) unsigned int*)l, 16, 0, 0);
}

__device__ __forceinline__ unsigned short f2bf(float f) {
  union { float f; unsigned u; } v; v.f = f;
  return (unsigned short)((v.u + 0x7FFFu + ((v.u >> 16) & 1u)) >> 16);
}

// ---------------- kernel 0: fp32 -> bf16 conversion ----------------
__global__ void convert_kernel(const float* __restrict__ x,
                               const float* __restrict__ wq, const float* __restrict__ wk,
                               const float* __restrict__ wv, const float* __restrict__ wo,
                               unsigned short* __restrict__ xbf,
                               unsigned short* __restrict__ wqb, unsigned short* __restrict__ wkb,
                               unsigned short* __restrict__ wvb, unsigned short* __restrict__ wob) {
  long t = (long)blockIdx.x * blockDim.x + threadIdx.x;  // 1M threads
  long base = t * 8;
  const float* src; unsigned short* dst; long off;
  if (base < 4194304L) { src = x; dst = xbf; off = base; }
  else {
    long r = base - 4194304L; int j = (int)(r >> 20); off = r & 1048575L;
    src = (j==0)?wq:(j==1)?wk:(j==2)?wv:wo;
    dst = (j==0)?wqb:(j==1)?wkb:(j==2)?wvb:wob;
  }
  const float4* s4 = (const float4*)(src + off);
  float4 a = s4[0], b = s4[1];
  ushort8 o;
  o[0]=f2bf(a.x); o[1]=f2bf(a.y); o[2]=f2bf(a.z); o[3]=f2bf(a.w);
  o[4]=f2bf(b.x); o[5]=f2bf(b.y); o[6]=f2bf(b.z); o[7]=f2bf(b.w);
  *(ushort8*)(dst + off) = o;
}

// ---- shared GEMM K-loop: 3-buffer LDS, 2-deep prefetch, SINGLE barrier (R9) ----
#define GS_STAGE(kbuf, kt) { \
    const size_t kb_ = (size_t)(kt) * 64; \
    char* d_ = lds + (kbuf) * 16384 + tid * 16; \
    gload_lds16(a0 + kb_, d_); \
    gload_lds16(a1 + kb_, d_ + 4096); \
    gload_lds16(b0 + kb_, d_ + 8192); \
    gload_lds16(b1 + kb_, d_ + 12288); \
  }

template<bool SWAP>
__device__ __forceinline__ void gemm_kloop(
    const char* a0, const char* a1, const char* b0, const char* b1,
    char* lds, const int tid, const int (&aoff)[4], const int (&boff)[4],
    f32x4 (&acc)[4][4]) {
  GS_STAGE(0, 0);
  GS_STAGE(1, 1);
  int cur = 0;
  for (int kt = 0; kt < 32; ++kt) {
    if (kt < 31) {
      asm volatile("s_waitcnt vmcnt(4)" ::: "memory");
    } else {
      asm volatile("s_waitcnt vmcnt(0)" ::: "memory");
    }
    __builtin_amdgcn_s_barrier();
    if (kt < 30) {
      int sb = cur + 2; if (sb >= 3) sb -= 3;
      GS_STAGE(sb, kt + 2);
    }
    const char* Ts = lds + cur * 16384;
    bf16x8 af[4], bfv[4];
#pragma unroll
    for (int mt=0; mt<4; ++mt) af[mt] = *(const bf16x8*)(Ts + aoff[mt]);
#pragma unroll
    for (int nt=0; nt<4; ++nt) bfv[nt] = *(const bf16x8*)(Ts + boff[nt]);
#pragma unroll
    for (int mt=0; mt<4; ++mt)
#pragma unroll
      for (int nt=0; nt<4; ++nt)
        acc[mt][nt] = SWAP ? MFMA16(bfv[nt], af[mt], acc[mt][nt])
                           : MFMA16(af[mt], bfv[nt], acc[mt][nt]);
    cur = (cur == 2) ? 0 : cur + 1;
  }
}

// ---------------- kernel 1: fused QKV projection GEMM (R9) ----------------
__global__ __launch_bounds__(256) void qkv_gemm(
    const bf16* __restrict__ xbf,
    const bf16* __restrict__ wqb, const bf16* __restrict__ wkb, const bf16* __restrict__ wvb,
    const float* __restrict__ bq, const float* __restrict__ bk, const float* __restrict__ bv,
    bf16* __restrict__ Q, bf16* __restrict__ K, bf16* __restrict__ VT) {
  __shared__ char lds[49152] __attribute__((aligned(16)));
  const int tid = threadIdx.x;
  const int bm = blockIdx.y * 128;
  const int bnG = blockIdx.x * 128;
  const int proj = bnG >> 10;
  const int bn = bnG & 1023;
  const bf16* wsel = (proj==0)?wqb:(proj==1)?wkb:wvb;
  const float* bias = (proj==0)?bq:(proj==1)?bk:bv;

  const int lane = tid & 63, w = tid >> 6;
  const int wm = (w>>1)*64, wn = (w&1)*64;
  const int c = lane & 15, g = lane >> 4;

  const int sr = tid >> 2;
  const int scb = ((tid & 3) * 16) ^ ((sr & 3) << 4);
  const char* a0 = (const char*)xbf  + ((size_t)(bm + sr     ) * 1024) * 2 + scb;
  const char* a1 = (const char*)xbf  + ((size_t)(bm + 64 + sr) * 1024) * 2 + scb;
  const char* b0 = (const char*)wsel + ((size_t)(bn + sr     ) * 1024) * 2 + scb;
  const char* b1 = (const char*)wsel + ((size_t)(bn + 64 + sr) * 1024) * 2 + scb;

  int aoff[4], boff[4];
#pragma unroll
  for (int mt=0; mt<4; ++mt) { int rr = wm + mt*16 + c; aoff[mt] = rr*64 + ((g*16) ^ ((rr&3)<<4)); }
#pragma unroll
  for (int nt=0; nt<4; ++nt) { int rr = wn + nt*16 + c; boff[nt] = 8192 + rr*64 + ((g*16) ^ ((rr&3)<<4)); }

  f32x4 acc[4][4];
#pragma unroll
  for (int mt=0; mt<4; ++mt)
#pragma unroll
    for (int nt=0; nt<4; ++nt) acc[mt][nt] = (f32x4){0.f,0.f,0.f,0.f};

  const int bidx = bm >> 11;
  const int srow = bm & 2047;

  if (proj != 2) {
    gemm_kloop<true>(a0, a1, b0, b1, lds, tid, aoff, boff, acc);
    bf16* dst = (proj == 0) ? Q : K;
    const float qs = (proj == 0) ? QSCALE : 1.0f;
#pragma unroll
    for (int nt=0; nt<4; ++nt) {
      const int n0 = bn + wn + nt*16 + g*4;
      const float4 b4 = *(const float4*)(bias + n0);
      const int h = n0 >> 6, d0 = n0 & 63;
#pragma unroll
      for (int mt=0; mt<4; ++mt) {
        const int s = srow + wm + mt*16 + c;
        bf16x4 pk;
        pk[0] = (bf16)((acc[mt][nt][0] + b4.x) * qs);
        pk[1] = (bf16)((acc[mt][nt][1] + b4.y) * qs);
        pk[2] = (bf16)((acc[mt][nt][2] + b4.z) * qs);
        pk[3] = (bf16)((acc[mt][nt][3] + b4.w) * qs);
        *(bf16x4*)(dst + (((size_t)(bidx*16 + h))*2048 + s)*64 + d0) = pk;
      }
    }
  } else {
    gemm_kloop<false>(a0, a1, b0, b1, lds, tid, aoff, boff, acc);
#pragma unroll
    for (int nt=0; nt<4; ++nt) {
      const int n = bn + wn + nt*16 + c;
      const float bv_ = bias[n];
      const int h = n >> 6, d = n & 63;
#pragma unroll
      for (int mt=0; mt<4; ++mt) {
        const int m0 = wm + mt*16 + g*4;
        bf16x4 pk;
#pragma unroll
        for (int r=0;r<4;++r) pk[r] = (bf16)(acc[mt][nt][r] + bv_);
        *(bf16x4*)(VT + (((size_t)(bidx*16 + h))*64 + d)*2048 + (srow + m0)) = pk;
      }
    }
  }
}

// ---------------- kernel 2: flash attention v4 — 8 waves, 32x32 MFMA ----------------
// grid = (S/256, B*H), 512 threads = 8 waves, wave owns 32 q-rows. KVBLK=64.
// K tile [64 keys][64 d] and V^T tile [64 d][64 keys] in LDS (shared by 8 waves),
// dbuf + single-barrier loop (R9-proven). chunk16 ^= row&7 swizzle both sides.
// Swapped QK^T (mfma32(K,Q)): lane holds 32 scores for q=lane&31; softmax is
// in-lane + 1 shfl_xor(32). P redistributed to PV B-operand via 8 shfl_xor(32)
// of packed bf16x2 pairs (T12 pattern).
__global__ __launch_bounds__(512) void attn_kernel(
    const bf16* __restrict__ Q, const bf16* __restrict__ K,
    const bf16* __restrict__ VT, bf16* __restrict__ attn_out) {
  __shared__ char alds[32768] __attribute__((aligned(16)));
  const int tid = threadIdx.x;
  const int L = tid & 63, wid = tid >> 6;
  const int q5 = L & 31, h = L >> 5;
  const int bh = blockIdx.y;                      // b*16 + head
  const int qbase = blockIdx.x * 256;
  const bf16* Qh = Q + (size_t)bh * 2048 * 64;
  const char* Khb = (const char*)(K  + (size_t)bh * 2048 * 64);
  const char* Vhb = (const char*)(VT + (size_t)bh * 64 * 2048);

  // staging (512 thr x 16B = one 8KB tile per instruction):
  // LDS(row, ch) <- global(row, ch ^ (row&7)); row = tid>>3, ch = tid&7
  const int srow = tid >> 3, sch = tid & 7;
  const int ssw = ((sch ^ (srow & 7)) << 4);
  const char* srcK = Khb + (size_t)srow * 128  + ssw;   // + kv*128
  const char* srcV = Vhb + (size_t)srow * 4096 + ssw;   // + kv*2

#define ATT_STAGE(buf, kv) { \
    gload_lds16(srcK + (size_t)(kv) * 128, alds + (buf) * 16384 + tid * 16); \
    gload_lds16(srcV + (size_t)(kv) * 2,   alds + (buf) * 16384 + 8192 + tid * 16); \
  }

  // Q fragments (B-operand): lane -> q = qbase + wid*32 + q5, k = 8h+e over d-window 16*dk
  const int qrow = qbase + wid * 32 + q5;
  bf16x8 qf[4];
#pragma unroll
  for (int dk = 0; dk < 4; ++dk)
    qf[dk] = *(const bf16x8*)(Qh + (size_t)qrow * 64 + dk * 16 + h * 8);

  f32x16 o0 = {0,0,0,0,0,0,0,0,0,0,0,0,0,0,0,0};
  f32x16 o1 = {0,0,0,0,0,0,0,0,0,0,0,0,0,0,0,0};
  float m = -1e30f, l = 0.f;

  ATT_STAGE(0, 0);
  asm volatile("s_waitcnt vmcnt(0)" ::: "memory");
  __builtin_amdgcn_s_barrier();

  for (int t = 0; t < 32; ++t) {
    const int cur = t & 1;
    if (t < 31) ATT_STAGE(cur ^ 1, (t + 1) * 64);

    const char* Kl = alds + cur * 16384;
    const char* Vl = Kl + 8192;

    // QK^T: st_s = scores for keys s*32 + (r&3)+8*(r>>2)+4h, q = q5
    f32x16 st0 = {0,0,0,0,0,0,0,0,0,0,0,0,0,0,0,0};
    f32x16 st1 = {0,0,0,0,0,0,0,0,0,0,0,0,0,0,0,0};
#pragma unroll
    for (int dk = 0; dk < 4; ++dk) {
      const int r0 = q5;            // A rows: keys 0-31
      bf16x8 k0 = *(const bf16x8*)(Kl + r0*128        + (((2*dk + h) ^ (r0 & 7)) << 4));
      const int r1 = 32 + q5;       // A rows: keys 32-63
      bf16x8 k1 = *(const bf16x8*)(Kl + r1*128        + (((2*dk + h) ^ (r1 & 7)) << 4));
      st0 = MFMA32(k0, qf[dk], st0);
      st1 = MFMA32(k1, qf[dk], st1);
    }

    // in-lane max over 32 + pair reduce
    float tmax = -1e30f;
#pragma unroll
    for (int r = 0; r < 16; ++r) { tmax = fmaxf(tmax, st0[r]); tmax = fmaxf(tmax, st1[r]); }
    tmax = fmaxf(tmax, __shfl_xor(tmax, 32, 64));
    if (!__all(tmax <= m + 8.f)) {                 // defer-max (THR=8)
      const float mnew = fmaxf(m, tmax);
      const float corr = __builtin_exp2f(m - mnew);
      l *= corr;
      o0 *= corr; o1 *= corr;
      m = mnew;
    }

    // exp2 + pack pairs: pkS[j][a] = bf16x2(p[4j+2a], p[4j+2a+1]) = keys 32s+8j+4h+2a+{0,1}
    unsigned pk0[4][2], pk1[4][2];
    float ps = 0.f;
#pragma unroll
    for (int j = 0; j < 4; ++j)
#pragma unroll
      for (int a = 0; a < 2; ++a) {
        {
          float x0 = __builtin_exp2f(st0[4*j+2*a]     - m);
          float x1 = __builtin_exp2f(st0[4*j+2*a + 1] - m);
          ps += x0 + x1;
          union { bf16x2 v; unsigned u; } z; z.v[0] = (bf16)x0; z.v[1] = (bf16)x1;
          pk0[j][a] = z.u;
        }
        {
          float x0 = __builtin_exp2f(st1[4*j+2*a]     - m);
          float x1 = __builtin_exp2f(st1[4*j+2*a + 1] - m);
          ps += x0 + x1;
          union { bf16x2 v; unsigned u; } z; z.v[0] = (bf16)x0; z.v[1] = (bf16)x1;
          pk1[j][a] = z.u;
        }
      }
    ps += __shfl_xor(ps, 32, 64);
    l += ps;

    // Assemble PV B-frags: frag c covers keys 16c+8h+{0..7} for this lane.
    // word w: (w>>1)==h -> own pkS[2cl+h][w&1]; else partner's pkS[2cl+h][w&1]
    // (shuffle expr must use index 2cl+(1-h) so the partner evaluates 2cl+h_mine).
    bf16x8 pf[4];
#pragma unroll
    for (int c = 0; c < 4; ++c) {
      const int cl = c & 1;
      unsigned own0, own1, snd0, snd1;
      if (c < 2) {
        own0 = h ? pk0[2*cl+1][0] : pk0[2*cl][0];
        own1 = h ? pk0[2*cl+1][1] : pk0[2*cl][1];
        snd0 = h ? pk0[2*cl][0]   : pk0[2*cl+1][0];
        snd1 = h ? pk0[2*cl][1]   : pk0[2*cl+1][1];
      } else {
        own0 = h ? pk1[2*cl+1][0] : pk1[2*cl][0];
        own1 = h ? pk1[2*cl+1][1] : pk1[2*cl][1];
        snd0 = h ? pk1[2*cl][0]   : pk1[2*cl+1][0];
        snd1 = h ? pk1[2*cl][1]   : pk1[2*cl+1][1];
      }
      unsigned sx0 = (unsigned)__shfl_xor((int)snd0, 32, 64);
      unsigned sx1 = (unsigned)__shfl_xor((int)snd1, 32, 64);
      union { unsigned u[4]; bf16x8 v; } fr;
      fr.u[0] = h ? sx0 : own0;
      fr.u[1] = h ? sx1 : own1;
      fr.u[2] = h ? own0 : sx0;
      fr.u[3] = h ? own1 : sx1;
      pf[c] = fr.v;
    }

    // PV: o_dblk += V^T[d = 32*dblk + rows][keys 16c+8h+e] x P
#pragma unroll
    for (int c = 0; c < 4; ++c) {
      const int r0 = q5;            // d rows 0-31
      bf16x8 v0 = *(const bf16x8*)(Vl + r0*128        + (((2*c + h) ^ (r0 & 7)) << 4));
      const int r1 = 32 + q5;       // d rows 32-63
      bf16x8 v1 = *(const bf16x8*)(Vl + r1*128        + (((2*c + h) ^ (r1 & 7)) << 4));
      o0 = MFMA32(v0, pf[c], o0);
      o1 = MFMA32(v1, pf[c], o1);
    }

    if (t < 31) {
      asm volatile("s_waitcnt vmcnt(0)" ::: "memory");   // stage(t+1) landed
      __builtin_amdgcn_s_barrier();
    }
  }
#undef ATT_STAGE

  // epilogue: D layout col=q5, row = (r&3)+8*(r>>2)+4h (+32 for o1)
  const float inv = 1.0f / l;
  const int b = bh >> 4, hh = bh & 15;
  bf16* outrow = attn_out + ((size_t)(b*2048 + qrow))*1024 + hh*64;
#pragma unroll
  for (int j = 0; j < 4; ++j) {
    bf16x4 ov;
#pragma unroll
    for (int i = 0; i < 4; ++i) ov[i] = (bf16)(o0[4*j+i] * inv);
    *(bf16x4*)(outrow + 8*j + 4*h) = ov;
#pragma unroll
    for (int i = 0; i < 4; ++i) ov[i] = (bf16)(o1[4*j+i] * inv);
    *(bf16x4*)(outrow + 32 + 8*j + 4*h) = ov;
  }
}

// ---------------- kernel 3: output projection GEMM (R9) ----------------
__global__ __launch_bounds__(256) void out_gemm(
    const bf16* __restrict__ A, const bf16* __restrict__ W,
    const float* __restrict__ bias, float* __restrict__ out) {
  __shared__ char lds[36864] __attribute__((aligned(16)));
  const int tid = threadIdx.x;
  const int bm = blockIdx.y * 64, bn = blockIdx.x * 128;
  const int lane = tid & 63, w = tid >> 6;
  const int c = lane & 15, g = lane >> 4;

  const int sr = tid >> 2;
  const int scb = ((tid & 3) * 16) ^ ((sr & 3) << 4);
  const char* a0 = (const char*)A + ((size_t)(bm + sr     ) * 1024) * 2 + scb;
  const char* b0 = (const char*)W + ((size_t)(bn + sr     ) * 1024) * 2 + scb;
  const char* b1 = (const char*)W + ((size_t)(bn + 64 + sr) * 1024) * 2 + scb;

#define OUT_STAGE(kbuf, kt) { \
    const size_t kb_ = (size_t)(kt) * 64; \
    char* d_ = lds + (kbuf) * 12288 + tid * 16; \
    gload_lds16(a0 + kb_, d_); \
    gload_lds16(b0 + kb_, d_ + 4096); \
    gload_lds16(b1 + kb_, d_ + 8192); \
  }

  int aoff[4], boff[2];
#pragma unroll
  for (int mt=0; mt<4; ++mt) { int rr = mt*16 + c; aoff[mt] = rr*64 + ((g*16) ^ ((rr&3)<<4)); }
#pragma unroll
  for (int nt=0; nt<2; ++nt) { int rr = w*32 + nt*16 + c; boff[nt] = 4096 + rr*64 + ((g*16) ^ ((rr&3)<<4)); }

  f32x4 acc[4][2];
#pragma unroll
  for (int mt=0; mt<4; ++mt)
#pragma unroll
    for (int nt=0; nt<2; ++nt) acc[mt][nt] = (f32x4){0.f,0.f,0.f,0.f};

  OUT_STAGE(0, 0);
  OUT_STAGE(1, 1);
  int cur = 0;
  for (int kt = 0; kt < 32; ++kt) {
    if (kt < 31) {
      asm volatile("s_waitcnt vmcnt(3)" ::: "memory");
    } else {
      asm volatile("s_waitcnt vmcnt(0)" ::: "memory");
    }
    __builtin_amdgcn_s_barrier();
    if (kt < 30) {
      int sb = cur + 2; if (sb >= 3) sb -= 3;
      OUT_STAGE(sb, kt + 2);
    }
    const char* Ts = lds + cur * 12288;
    bf16x8 af[4], bfv[2];
#pragma unroll
    for (int mt=0; mt<4; ++mt) af[mt] = *(const bf16x8*)(Ts + aoff[mt]);
#pragma unroll
    for (int nt=0; nt<2; ++nt) bfv[nt] = *(const bf16x8*)(Ts + boff[nt]);
#pragma unroll
    for (int mt=0; mt<4; ++mt)
#pragma unroll
      for (int nt=0; nt<2; ++nt)
        acc[mt][nt] = MFMA16(bfv[nt], af[mt], acc[mt][nt]);
    cur = (cur == 2) ? 0 : cur + 1;
  }
#undef OUT_STAGE

#pragma unroll
  for (int nt=0; nt<2; ++nt) {
    const int n0 = bn + w*32 + nt*16 + g*4;
    const float4 b4 = *(const float4*)(bias + n0);
#pragma unroll
    for (int mt=0; mt<4; ++mt) {
      const int m0 = bm + mt*16 + c;
      float4 ov;
      ov.x = acc[mt][nt][0] + b4.x;
      ov.y = acc[mt][nt][1] + b4.y;
      ov.z = acc[mt][nt][2] + b4.z;
      ov.w = acc[mt][nt][3] + b4.w;
      *(float4*)(out + (size_t)m0*1024 + n0) = ov;
    }
  }
}

// ---------------- launch ----------------
extern "C" void kernel_launch(void* const* d_in, const int* in_sizes, int n_in,
                              void* d_out, int out_size, void* d_ws, size_t ws_size,
                              hipStream_t stream) {
  const float* x  = (const float*)d_in[0];
  const float* Wq = (const float*)d_in[1];
  const float* bq = (const float*)d_in[2];
  const float* Wk = (const float*)d_in[3];
  const float* bk = (const float*)d_in[4];
  const float* Wv = (const float*)d_in[5];
  const float* bv = (const float*)d_in[6];
  const float* Wo = (const float*)d_in[7];
  const float* bo = (const float*)d_in[8];

  char* ws = (char*)d_ws;
  const size_t MiB = 1u << 20;
  unsigned short* xbf = (unsigned short*)(ws);              // 8 MiB
  unsigned short* wqb = (unsigned short*)(ws +  8*MiB);     // 2 MiB
  unsigned short* wkb = (unsigned short*)(ws + 10*MiB);
  unsigned short* wvb = (unsigned short*)(ws + 12*MiB);
  unsigned short* wob = (unsigned short*)(ws + 14*MiB);
  bf16* Qb    = (bf16*)(ws + 16*MiB);                       // 8 MiB [B,H,S,DH]
  bf16* Kb    = (bf16*)(ws + 24*MiB);                       // 8 MiB [B,H,S,DH]
  bf16* VTb   = (bf16*)(ws + 32*MiB);                       // 8 MiB [B,H,DH,S]
  bf16* attnb = (bf16*)(ws + 40*MiB);                       // 8 MiB [M,E]

  convert_kernel<<<4096, 256, 0, stream>>>(x, Wq, Wk, Wv, Wo, xbf, wqb, wkb, wvb, wob);
  qkv_gemm<<<dim3(24, 32), 256, 0, stream>>>(
      (const bf16*)xbf, (const bf16*)wqb, (const bf16*)wkb, (const bf16*)wvb,
      bq, bk, bv, Qb, Kb, VTb);
  attn_kernel<<<dim3(8, 32), 512, 0, stream>>>(Qb, Kb, VTb, attnb);
  out_gemm<<<dim3(8, 64), 256, 0, stream>>>(attnb, (const bf16*)wob, bo, (float*)d_out);
}